// Round 1
// baseline (1201.200 us; speedup 1.0000x reference)
//
#include <hip/hip_runtime.h>

#define DIM   1024
#define HEADS 16
#define HD    64
#define BB    2
#define SS    2048
#define LLL   2048
#define LOG2E 1.4426950408889634f

typedef __bf16 bf16x8 __attribute__((ext_vector_type(8)));
typedef float  f32x4  __attribute__((ext_vector_type(4)));

static __device__ __forceinline__ unsigned short f2b(float x) {
  unsigned u = __float_as_uint(x);
  u += 0x7fffu + ((u >> 16) & 1u);
  return (unsigned short)(u >> 16);
}
static __device__ __forceinline__ float b2f(unsigned short u) {
  return __uint_as_float(((unsigned)u) << 16);
}

// ---------------- f32 -> bf16 convert (vectorized) ----------------
__global__ void cvt_f32_bf16(const float* __restrict__ src, unsigned short* __restrict__ dst, int n4) {
  int i = blockIdx.x * blockDim.x + threadIdx.x;
  if (i >= n4) return;
  float4 f = ((const float4*)src)[i];
  ushort4 o;
  o.x = f2b(f.x); o.y = f2b(f.y); o.z = f2b(f.z); o.w = f2b(f.w);
  ((ushort4*)dst)[i] = o;
}

// ---------------- bf16 NT GEMM: C[M,N] = A[M,K] * Bt[N,K]^T + bias ----------------
template<int F32OUT>
__global__ __launch_bounds__(256) void gemm_nt(const unsigned short* __restrict__ A,
                                               const unsigned short* __restrict__ Bt,
                                               const float* __restrict__ bias,
                                               void* __restrict__ Cv,
                                               int M, int N, int K) {
  __shared__ unsigned short As[64][64];
  __shared__ unsigned short Bs[64][64];
  const int t = threadIdx.x;
  const int w = t >> 6, l = t & 63, g = l >> 4, li = l & 15;
  const int m0 = blockIdx.y * 64, n0 = blockIdx.x * 64;
  f32x4 acc[4] = {};
  for (int kt = 0; kt < K; kt += 64) {
#pragma unroll
    for (int s = 0; s < 2; ++s) {
      int slot = t + s * 256;
      int r = slot >> 3, c8 = (slot & 7) * 8;
      *(uint4*)&As[r][c8] = *(const uint4*)&A[(size_t)(m0 + r) * K + kt + c8];
      *(uint4*)&Bs[r][c8] = *(const uint4*)&Bt[(size_t)(n0 + r) * K + kt + c8];
    }
    __syncthreads();
#pragma unroll
    for (int kk = 0; kk < 2; ++kk) {
      bf16x8 a = *(const bf16x8*)&As[w * 16 + li][kk * 32 + g * 8];
#pragma unroll
      for (int ni = 0; ni < 4; ++ni) {
        bf16x8 b = *(const bf16x8*)&Bs[ni * 16 + li][kk * 32 + g * 8];
        acc[ni] = __builtin_amdgcn_mfma_f32_16x16x32_bf16(a, b, acc[ni], 0, 0, 0);
      }
    }
    __syncthreads();
  }
#pragma unroll
  for (int ni = 0; ni < 4; ++ni)
#pragma unroll
    for (int v = 0; v < 4; ++v) {
      int rr = m0 + w * 16 + g * 4 + v;
      int cc = n0 + ni * 16 + li;
      float val = acc[ni][v] + bias[cc];
      if (F32OUT) ((float*)Cv)[(size_t)rr * N + cc] = val;
      else        ((unsigned short*)Cv)[(size_t)rr * N + cc] = f2b(val);
    }
}

// ---------------- pass 1: softmax denominators (no max subtraction; scores ~N(0,1)) ----------------
__global__ __launch_bounds__(256) void denom_kernel(const unsigned short* __restrict__ qb,
                                                    const unsigned short* __restrict__ kb0,
                                                    const unsigned short* __restrict__ kb1,
                                                    const int* __restrict__ mask,
                                                    float* __restrict__ invd) {
  __shared__ unsigned short Qs[32][64];
  __shared__ unsigned short Ks[64][64];
  __shared__ float Ms[32][64];
  __shared__ float dpart[4][16];
  const int qtile = blockIdx.x, h = blockIdx.y;
  const int b = blockIdx.z >> 1, layer = blockIdx.z & 1;
  const unsigned short* kb = layer ? kb1 : kb0;
  const int t = threadIdx.x;
  const int w = t >> 6, l = t & 63, g = l >> 4, li = l & 15;
  const int mi = w >> 1, nb = (w & 1) * 2;
  {
    int r = t >> 3, c8 = (t & 7) * 8;
    *(uint4*)&Qs[r][c8] = *(const uint4*)&qb[((size_t)(b * SS + qtile * 32 + r)) * DIM + h * HD + c8];
  }
  float racc[4] = {0.f, 0.f, 0.f, 0.f};
  for (int lt = 0; lt < LLL / 64; ++lt) {
#pragma unroll
    for (int s = 0; s < 2; ++s) {
      int slot = t + s * 256;
      int r = slot >> 3, c8 = (slot & 7) * 8;
      *(uint4*)&Ks[r][c8] = *(const uint4*)&kb[((size_t)(b * LLL + lt * 64 + r)) * DIM + h * HD + c8];
    }
    if (layer == 0) {
      int r = t >> 3, c8 = (t & 7) * 8;
#pragma unroll
      for (int i = 0; i < 8; i += 4) {
        int4 mm = *(const int4*)&mask[(size_t)(qtile * 32 + r) * LLL + lt * 64 + c8 + i];
        Ms[r][c8 + i + 0] = mm.x ? 1.f : 0.f;
        Ms[r][c8 + i + 1] = mm.y ? 1.f : 0.f;
        Ms[r][c8 + i + 2] = mm.z ? 1.f : 0.f;
        Ms[r][c8 + i + 3] = mm.w ? 1.f : 0.f;
      }
    }
    __syncthreads();
#pragma unroll
    for (int ni = 0; ni < 2; ++ni) {
      f32x4 sacc = {};
#pragma unroll
      for (int kk = 0; kk < 2; ++kk) {
        bf16x8 a = *(const bf16x8*)&Qs[mi * 16 + li][kk * 32 + g * 8];
        bf16x8 bb = *(const bf16x8*)&Ks[(nb + ni) * 16 + li][kk * 32 + g * 8];
        sacc = __builtin_amdgcn_mfma_f32_16x16x32_bf16(a, bb, sacc, 0, 0, 0);
      }
#pragma unroll
      for (int v = 0; v < 4; ++v) {
        int r = mi * 16 + g * 4 + v, c = (nb + ni) * 16 + li;
        float e = exp2f(sacc[v] * (0.125f * LOG2E));
        if (layer == 0) e *= Ms[r][c];
        racc[v] += e;
      }
    }
    __syncthreads();
  }
#pragma unroll
  for (int off = 1; off < 16; off <<= 1)
#pragma unroll
    for (int v = 0; v < 4; ++v) racc[v] += __shfl_xor(racc[v], off, 64);
  if (li == 0) {
#pragma unroll
    for (int v = 0; v < 4; ++v) dpart[w][g * 4 + v] = racc[v];
  }
  __syncthreads();
  if (t < 32) {
    int m2 = t >> 4, r = t & 15;
    float d = dpart[2 * m2][r] + dpart[2 * m2 + 1][r];
    invd[(((size_t)layer * BB + b) * HEADS + h) * SS + qtile * 32 + t] = 1.0f / d;
  }
}

// ---------------- pass 2: full attention, all heads per block; writes head-mean directly ----------------
__global__ __launch_bounds__(512) void attn_kernel(const unsigned short* __restrict__ qb,
                                                   const unsigned short* __restrict__ kb0,
                                                   const unsigned short* __restrict__ vb0,
                                                   const unsigned short* __restrict__ kb1,
                                                   const unsigned short* __restrict__ vb1,
                                                   const int* __restrict__ mask,
                                                   const float* __restrict__ invd,
                                                   unsigned short* __restrict__ out01,
                                                   float* __restrict__ aout) {
  __shared__ unsigned short Qs[32][1024];
  __shared__ unsigned short Ks[64][64];
  __shared__ unsigned short Vt[64][64];   // transposed V tile: Vt[d][l]
  __shared__ unsigned short Wsm[32][64];  // bf16 probabilities for PV
  __shared__ float Asum[32][64];          // sum over heads of w
  __shared__ float Ms[32][64];
  __shared__ float Dinv[16][32];
  const int qtile = blockIdx.x, layer = blockIdx.y, b = blockIdx.z;
  const unsigned short* kb = layer ? kb1 : kb0;
  const unsigned short* vb = layer ? vb1 : vb0;
  const int t = threadIdx.x;
  const int w = t >> 6, l = t & 63, g = l >> 4, li = l & 15;
  const int wm = w >> 2, wn = w & 3;
#pragma unroll
  for (int s = 0; s < 8; ++s) {
    int slot = t + s * 512;
    int r = slot >> 7, c8 = (slot & 127) * 8;
    *(uint4*)&Qs[r][c8] = *(const uint4*)&qb[((size_t)(b * SS + qtile * 32 + r)) * DIM + c8];
  }
  {
    int hh = t >> 5, r = t & 31;
    Dinv[hh][r] = invd[(((size_t)layer * BB + b) * HEADS + hh) * SS + qtile * 32 + r];
  }
  f32x4 accP[16] = {};
  float* __restrict__ aL = aout + (size_t)layer * BB * SS * LLL;
  for (int lt = 0; lt < LLL / 64; ++lt) {
    {
      int r = t >> 4, c4 = (t & 15) * 4;
      *(float4*)&Asum[r][c4] = make_float4(0.f, 0.f, 0.f, 0.f);
      if (layer == 0) {
        int4 mm = *(const int4*)&mask[(size_t)(qtile * 32 + r) * LLL + lt * 64 + c4];
        Ms[r][c4 + 0] = mm.x ? 1.f : 0.f;
        Ms[r][c4 + 1] = mm.y ? 1.f : 0.f;
        Ms[r][c4 + 2] = mm.z ? 1.f : 0.f;
        Ms[r][c4 + 3] = mm.w ? 1.f : 0.f;
      }
    }
    __syncthreads();
#pragma unroll
    for (int h = 0; h < HEADS; ++h) {
      {
        int r = t >> 3, c8 = (t & 7) * 8;
        *(uint4*)&Ks[r][c8] = *(const uint4*)&kb[((size_t)(b * LLL + lt * 64 + r)) * DIM + h * HD + c8];
        uint4 vv = *(const uint4*)&vb[((size_t)(b * LLL + lt * 64 + r)) * DIM + h * HD + c8];
        const unsigned short* vp = (const unsigned short*)&vv;
#pragma unroll
        for (int i = 0; i < 8; ++i) Vt[c8 + i][r] = vp[i];
      }
      __syncthreads();
      f32x4 sacc = {};
#pragma unroll
      for (int kk = 0; kk < 2; ++kk) {
        bf16x8 a  = *(const bf16x8*)&Qs[wm * 16 + li][h * HD + kk * 32 + g * 8];
        bf16x8 bb = *(const bf16x8*)&Ks[wn * 16 + li][kk * 32 + g * 8];
        sacc = __builtin_amdgcn_mfma_f32_16x16x32_bf16(a, bb, sacc, 0, 0, 0);
      }
#pragma unroll
      for (int v = 0; v < 4; ++v) {
        int r = wm * 16 + g * 4 + v, c = wn * 16 + li;
        float e = exp2f(sacc[v] * (0.125f * LOG2E));
        if (layer == 0) e *= Ms[r][c];
        float wv = e * Dinv[h][r];
        Asum[r][c] += wv;
        Wsm[r][c] = f2b(wv);
      }
      __syncthreads();
#pragma unroll
      for (int kk = 0; kk < 2; ++kk) {
        bf16x8 aw = *(const bf16x8*)&Wsm[wm * 16 + li][kk * 32 + g * 8];
        bf16x8 bv = *(const bf16x8*)&Vt[wn * 16 + li][kk * 32 + g * 8];
        accP[h] = __builtin_amdgcn_mfma_f32_16x16x32_bf16(aw, bv, accP[h], 0, 0, 0);
      }
      __syncthreads();
    }
    {
      int r = t >> 4, c4 = (t & 15) * 4;
      float4 av = *(const float4*)&Asum[r][c4];
      float4 o = make_float4(av.x * 0.0625f, av.y * 0.0625f, av.z * 0.0625f, av.w * 0.0625f);
      *(float4*)&aL[((size_t)(b * SS + qtile * 32 + r)) * LLL + lt * 64 + c4] = o;
    }
    // no trailing sync needed: next-iter zero/store touches same cells by same thread,
    // and all cross-thread reads of Asum/Ms for this lt completed before the last barrier.
  }
#pragma unroll
  for (int h = 0; h < HEADS; ++h)
#pragma unroll
    for (int v = 0; v < 4; ++v) {
      int r = qtile * 32 + wm * 16 + g * 4 + v;
      int c = h * HD + wn * 16 + li;
      out01[(((size_t)layer * BB + b) * SS + r) * DIM + c] = f2b(accP[h][v]);
    }
}

// ---------------- gated merge: merged = bf16(g*out0 + (1-g)*out1) ----------------
__global__ void merge_kernel(const unsigned short* __restrict__ o01,
                             const float* __restrict__ gate,
                             unsigned short* __restrict__ merged) {
  int i = blockIdx.x * blockDim.x + threadIdx.x;  // one ushort4 per thread
  float gv = gate[0];
  float g = 1.0f / (1.0f + exp2f(-gv * LOG2E));
  const size_t n = (size_t)BB * SS * DIM;
  ushort4 a = ((const ushort4*)o01)[i];
  ushort4 c = ((const ushort4*)(o01 + n))[i];
  ushort4 o;
  o.x = f2b(g * b2f(a.x) + (1.f - g) * b2f(c.x));
  o.y = f2b(g * b2f(a.y) + (1.f - g) * b2f(c.y));
  o.z = f2b(g * b2f(a.z) + (1.f - g) * b2f(c.z));
  o.w = f2b(g * b2f(a.w) + (1.f - g) * b2f(c.w));
  ((ushort4*)merged)[i] = o;
}

extern "C" void kernel_launch(void* const* d_in, const int* in_sizes, int n_in,
                              void* d_out, int out_size, void* d_ws, size_t ws_size,
                              hipStream_t stream) {
  const float* query = (const float*)d_in[0];
  const float* k0f   = (const float*)d_in[1];
  const float* v0f   = (const float*)d_in[2];
  const float* k1f   = (const float*)d_in[3];
  const float* v1f   = (const float*)d_in[4];
  const int*   mask  = (const int*)d_in[5];
  const float* bq    = (const float*)d_in[7];
  const float* Wqf   = (const float*)d_in[6];
  const float* Wof   = (const float*)d_in[8];
  const float* bo    = (const float*)d_in[9];
  const float* gate  = (const float*)d_in[10];
  float* out = (float*)d_out;

  const size_t nQ = (size_t)BB * SS * DIM;  // 4,194,304
  const size_t nW = (size_t)DIM * DIM;      // 1,048,576

  char* ws = (char*)d_ws;
  size_t off = 0;
  auto alloc = [&](size_t bytes) -> char* {
    char* p = ws + off;
    off += (bytes + 255) & ~(size_t)255;
    return p;
  };
  unsigned short* queryb  = (unsigned short*)alloc(nQ * 2);
  unsigned short* wqb     = (unsigned short*)alloc(nW * 2);
  unsigned short* wob     = (unsigned short*)alloc(nW * 2);
  unsigned short* kb0     = (unsigned short*)alloc(nQ * 2);
  unsigned short* vb0     = (unsigned short*)alloc(nQ * 2);
  unsigned short* kb1     = (unsigned short*)alloc(nQ * 2);
  unsigned short* vb1     = (unsigned short*)alloc(nQ * 2);
  unsigned short* qb      = (unsigned short*)alloc(nQ * 2);
  float*          invd    = (float*)alloc((size_t)2 * BB * HEADS * SS * sizeof(float));
  unsigned short* out01   = (unsigned short*)alloc((size_t)2 * nQ * 2);
  unsigned short* mergedb = (unsigned short*)alloc(nQ * 2);

  auto cvt = [&](const float* s, unsigned short* d, size_t n) {
    int n4 = (int)(n / 4);
    cvt_f32_bf16<<<dim3((n4 + 255) / 256), dim3(256), 0, stream>>>(s, d, n4);
  };
  cvt(query, queryb, nQ);
  cvt(Wqf, wqb, nW);
  cvt(Wof, wob, nW);
  cvt(k0f, kb0, nQ);
  cvt(v0f, vb0, nQ);
  cvt(k1f, kb1, nQ);
  cvt(v1f, vb1, nQ);

  // q projection: qb = bf16(query @ Wq^T + bq)
  gemm_nt<0><<<dim3(DIM / 64, (BB * SS) / 64), dim3(256), 0, stream>>>(
      queryb, wqb, bq, (void*)qb, BB * SS, DIM, DIM);

  // pass 1: softmax denominators per (layer,b,h,s)
  denom_kernel<<<dim3(SS / 32, HEADS, BB * 2), dim3(256), 0, stream>>>(
      qb, kb0, kb1, mask, invd);

  // pass 2: attention outputs + head-mean attention maps (a0/a1 straight into d_out)
  attn_kernel<<<dim3(SS / 32, 2, BB), dim3(512), 0, stream>>>(
      qb, kb0, vb0, kb1, vb1, mask, invd, out01, out + nQ);

  // gated merge to bf16
  merge_kernel<<<dim3((int)(nQ / 4 / 256)), dim3(256), 0, stream>>>(out01, gate, mergedb);

  // output projection: out = merged @ Wo^T + bo (f32 into d_out)
  gemm_nt<1><<<dim3(DIM / 64, (BB * SS) / 64), dim3(256), 0, stream>>>(
      mergedb, wob, bo, (void*)out, BB * SS, DIM, DIM);
}

// Round 2
// 745.779 us; speedup vs baseline: 1.6107x; 1.6107x over previous
//
#include <hip/hip_runtime.h>

#define DIM   1024
#define HEADS 16
#define HD    64
#define BB    2
#define SS    2048
#define LLL   2048
#define LOG2E 1.4426950408889634f

typedef __bf16 bf16x8 __attribute__((ext_vector_type(8)));
typedef float  f32x4  __attribute__((ext_vector_type(4)));
typedef short  s16x4  __attribute__((ext_vector_type(4)));
typedef unsigned short u16;

static __device__ __forceinline__ u16 f2b(float x) {
  unsigned u = __float_as_uint(x);
  u += 0x7fffu + ((u >> 16) & 1u);
  return (u16)(u >> 16);
}
static __device__ __forceinline__ float b2f(u16 u) {
  return __uint_as_float(((unsigned)u) << 16);
}
static __device__ __forceinline__ f32x4 mfma32(bf16x8 a, bf16x8 b, f32x4 c) {
  return __builtin_amdgcn_mfma_f32_16x16x32_bf16(a, b, c, 0, 0, 0);
}
static __device__ __forceinline__ f32x4 mfma16(s16x4 a, s16x4 b, f32x4 c) {
#if __has_builtin(__builtin_amdgcn_mfma_f32_16x16x16bf16_1k)
  return __builtin_amdgcn_mfma_f32_16x16x16bf16_1k(a, b, c, 0, 0, 0);
#else
  asm volatile("v_mfma_f32_16x16x16_bf16 %0, %1, %2, %0" : "+v"(c) : "v"(a), "v"(b));
  return c;
#endif
}

// ---------------- f32 -> bf16 convert ----------------
__global__ void cvt_f32_bf16(const float* __restrict__ src, u16* __restrict__ dst, int n4) {
  int i = blockIdx.x * blockDim.x + threadIdx.x;
  if (i >= n4) return;
  float4 f = ((const float4*)src)[i];
  ushort4 o;
  o.x = f2b(f.x); o.y = f2b(f.y); o.z = f2b(f.z); o.w = f2b(f.w);
  ((ushort4*)dst)[i] = o;
}

// ---------------- mask -> bitmask (u32 per 32 cols) ----------------
__global__ void mask_pack(const int* __restrict__ mask, unsigned* __restrict__ mbits) {
  int i = blockIdx.x * blockDim.x + threadIdx.x;  // over S*L/32
  const int* src = mask + (size_t)i * 32;
  unsigned bm = 0;
#pragma unroll
  for (int j = 0; j < 8; ++j) {
    int4 m = ((const int4*)src)[j];
    bm |= (m.x != 0 ? 1u : 0u) << (j * 4 + 0);
    bm |= (m.y != 0 ? 1u : 0u) << (j * 4 + 1);
    bm |= (m.z != 0 ? 1u : 0u) << (j * 4 + 2);
    bm |= (m.w != 0 ? 1u : 0u) << (j * 4 + 3);
  }
  mbits[i] = bm;
}

// ---------------- V (f32, [b][l][h*64+d]) -> Vt (bf16, [lay][b][h][d][L]) ----------------
__global__ __launch_bounds__(256) void vtrans(const float* __restrict__ v0,
                                              const float* __restrict__ v1,
                                              u16* __restrict__ Vt) {
  __shared__ u16 T[64][72];
  const int lt = blockIdx.x, h = blockIdx.y, z = blockIdx.z;
  const int lay = z >> 1, b = z & 1;
  const float* v = lay ? v1 : v0;
  const int t = threadIdx.x;
  {
    int r = t >> 2, c16 = (t & 3) * 16;
    const float* src = &v[((size_t)(b * LLL + lt * 64 + r)) * DIM + h * 64 + c16];
#pragma unroll
    for (int i = 0; i < 4; ++i) {
      float4 f = *(const float4*)&src[i * 4];
      T[r][c16 + i * 4 + 0] = f2b(f.x);
      T[r][c16 + i * 4 + 1] = f2b(f.y);
      T[r][c16 + i * 4 + 2] = f2b(f.z);
      T[r][c16 + i * 4 + 3] = f2b(f.w);
    }
  }
  __syncthreads();
  {
    int d = t >> 2, l16 = (t & 3) * 16;
    u16 u[16];
#pragma unroll
    for (int i = 0; i < 16; ++i) u[i] = T[l16 + i][d];
    u16* dst = &Vt[((((size_t)lay * BB + b) * HEADS + h) * HD + d) * LLL + lt * 64 + l16];
    *(uint4*)dst = *(uint4*)&u[0];
    *(uint4*)(dst + 8) = *(uint4*)&u[8];
  }
}

// ---------------- bf16 NT GEMM (swizzled LDS) ----------------
template<int F32OUT>
__global__ __launch_bounds__(256) void gemm_nt(const u16* __restrict__ A,
                                               const u16* __restrict__ Bt,
                                               const float* __restrict__ bias,
                                               void* __restrict__ Cv,
                                               int M, int N, int K) {
  __shared__ u16 As[64][64];
  __shared__ u16 Bs[64][64];
  const int t = threadIdx.x;
  const int w = t >> 6, l = t & 63, g = l >> 4, li = l & 15;
  const int m0 = blockIdx.y * 64, n0 = blockIdx.x * 64;
  f32x4 acc[4] = {};
  for (int kt = 0; kt < K; kt += 64) {
#pragma unroll
    for (int s = 0; s < 2; ++s) {
      int slot = t + s * 256;
      int r = slot >> 3, c8 = ((slot & 7) * 8) ^ ((r & 7) << 3);
      *(uint4*)&As[r][c8] = *(const uint4*)&A[(size_t)(m0 + r) * K + kt + ((slot & 7) * 8)];
      *(uint4*)&Bs[r][c8] = *(const uint4*)&Bt[(size_t)(n0 + r) * K + kt + ((slot & 7) * 8)];
    }
    __syncthreads();
#pragma unroll
    for (int kk = 0; kk < 2; ++kk) {
      int ra = w * 16 + li;
      bf16x8 a = *(const bf16x8*)&As[ra][(kk * 32 + g * 8) ^ ((ra & 7) << 3)];
#pragma unroll
      for (int ni = 0; ni < 4; ++ni) {
        int rb = ni * 16 + li;
        bf16x8 b = *(const bf16x8*)&Bs[rb][(kk * 32 + g * 8) ^ ((rb & 7) << 3)];
        acc[ni] = mfma32(a, b, acc[ni]);
      }
    }
    __syncthreads();
  }
#pragma unroll
  for (int ni = 0; ni < 4; ++ni)
#pragma unroll
    for (int v = 0; v < 4; ++v) {
      int rr = m0 + w * 16 + g * 4 + v;
      int cc = n0 + ni * 16 + li;
      float val = acc[ni][v] + bias[cc];
      if (F32OUT) ((float*)Cv)[(size_t)rr * N + cc] = val;
      else        ((u16*)Cv)[(size_t)rr * N + cc] = f2b(val);
    }
}

// ---------------- fused dual-pass attention ----------------
// grid: 256 blocks (XCD-chunked), block 512 = 8 waves, wave w owns heads {2w, 2w+1}.
// Phase 1: denominators (swapped QK^T in registers, shuffle-reduced).
// Phase 2: QK^T again, w = exp*mask*dinv; Asum cross-head via LDS Part; PV via
//          O^T = mfma_16x16x16(A=Vt frag, B=w^T packed from S^T C-regs directly).
__global__ __launch_bounds__(512) void attn_fused(const u16* __restrict__ qb,
                                                  const u16* __restrict__ kb0,
                                                  const u16* __restrict__ kb1,
                                                  const u16* __restrict__ Vt,
                                                  const unsigned* __restrict__ mbits,
                                                  u16* __restrict__ out01,
                                                  float* __restrict__ aout) {
  __shared__ float Part[8][32][64];
  const int flat = blockIdx.x;
  const int work = (flat & 7) * 32 + (flat >> 3);  // XCD-contiguous chunks
  const int lay = work >> 7, b = (work >> 6) & 1, qt = work & 63;
  const int masked = (lay == 0);
  const u16* kbb = (lay ? kb1 : kb0) + (size_t)b * LLL * DIM;
  const u16* vtb = Vt + (((size_t)lay * BB + b) * HEADS) * HD * LLL;
  u16* ob = out01 + ((size_t)lay * BB + b) * SS * DIM;
  float* ab = aout + ((size_t)lay * BB + b) * SS * LLL;

  const int t = threadIdx.x;
  const int w = t >> 6, l = t & 63, g = l >> 4, li = l & 15;
  const float SC = 0.125f * LOG2E;

  // persistent Q fragments (B-operand of swapped QK): Q[q=li+16n][d = h*64 + kk*32 + 8g..]
  bf16x8 qf[2][2][2];
  {
    const u16* qrow = qb + ((size_t)(b * SS + qt * 32)) * DIM;
#pragma unroll
    for (int hh = 0; hh < 2; ++hh)
#pragma unroll
      for (int n = 0; n < 2; ++n)
#pragma unroll
        for (int kk = 0; kk < 2; ++kk)
          qf[hh][n][kk] = *(const bf16x8*)&qrow[(size_t)(n * 16 + li) * DIM +
                                               (2 * w + hh) * HD + kk * 32 + g * 8];
  }

  // ---------- phase 1: denominators ----------
  float racc[2][2] = {};
  for (int lt = 0; lt < LLL / 64; ++lt) {
    unsigned mw[2][2];
    if (masked) {
#pragma unroll
      for (int n = 0; n < 2; ++n)
#pragma unroll
        for (int mh = 0; mh < 2; ++mh)
          mw[n][mh] = mbits[(size_t)(qt * 32 + n * 16 + li) * (LLL / 32) + lt * 2 + mh];
    }
#pragma unroll
    for (int hh = 0; hh < 2; ++hh) {
      f32x4 s[4][2] = {};
#pragma unroll
      for (int mt = 0; mt < 4; ++mt)
#pragma unroll
        for (int kk = 0; kk < 2; ++kk) {
          bf16x8 kf = *(const bf16x8*)&kbb[(size_t)(lt * 64 + mt * 16 + li) * DIM +
                                           (2 * w + hh) * HD + kk * 32 + g * 8];
#pragma unroll
          for (int n = 0; n < 2; ++n) s[mt][n] = mfma32(kf, qf[hh][n][kk], s[mt][n]);
        }
#pragma unroll
      for (int mt = 0; mt < 4; ++mt)
#pragma unroll
        for (int n = 0; n < 2; ++n)
#pragma unroll
          for (int v = 0; v < 4; ++v) {
            float e = __builtin_amdgcn_exp2f(s[mt][n][v] * SC);
            if (masked && !((mw[n][mt >> 1] >> ((mt & 1) * 16 + 4 * g + v)) & 1u)) e = 0.f;
            racc[hh][n] += e;
          }
    }
  }
  float dinv[2][2];
#pragma unroll
  for (int hh = 0; hh < 2; ++hh)
#pragma unroll
    for (int n = 0; n < 2; ++n) {
      float r = racc[hh][n];
      r += __shfl_xor(r, 16);
      r += __shfl_xor(r, 32);
      dinv[hh][n] = 1.0f / r;
    }

  // ---------- phase 2: attention + head-mean ----------
  f32x4 oacc[2][4][2] = {};  // [hh][dtile][n]
  for (int lt = 0; lt < LLL / 64; ++lt) {
    unsigned mw[2][2];
    if (masked) {
#pragma unroll
      for (int n = 0; n < 2; ++n)
#pragma unroll
        for (int mh = 0; mh < 2; ++mh)
          mw[n][mh] = mbits[(size_t)(qt * 32 + n * 16 + li) * (LLL / 32) + lt * 2 + mh];
    }
    f32x4 asum[4][2] = {};  // S^T C-layout: [l-tile][q-tile], v = l fine index
#pragma unroll
    for (int hh = 0; hh < 2; ++hh) {
      f32x4 s[4][2] = {};
#pragma unroll
      for (int mt = 0; mt < 4; ++mt)
#pragma unroll
        for (int kk = 0; kk < 2; ++kk) {
          bf16x8 kf = *(const bf16x8*)&kbb[(size_t)(lt * 64 + mt * 16 + li) * DIM +
                                           (2 * w + hh) * HD + kk * 32 + g * 8];
#pragma unroll
          for (int n = 0; n < 2; ++n) s[mt][n] = mfma32(kf, qf[hh][n][kk], s[mt][n]);
        }
#pragma unroll
      for (int mt = 0; mt < 4; ++mt) {
        s16x4 wpk[2];
#pragma unroll
        for (int n = 0; n < 2; ++n)
#pragma unroll
          for (int v = 0; v < 4; ++v) {
            float e = __builtin_amdgcn_exp2f(s[mt][n][v] * SC);
            if (masked && !((mw[n][mt >> 1] >> ((mt & 1) * 16 + 4 * g + v)) & 1u)) e = 0.f;
            e *= dinv[hh][n];
            asum[mt][n][v] += e;
            wpk[n][v] = (short)f2b(e);
          }
        // PV: O^T[d][q] += V^T-frag * w^T-frag  (k = this mt's 16 l values)
#pragma unroll
        for (int dt = 0; dt < 4; ++dt) {
          s16x4 vf = *(const s16x4*)&vtb[((size_t)((2 * w + hh) * HD + dt * 16 + li)) * LLL +
                                         lt * 64 + mt * 16 + 4 * g];
#pragma unroll
          for (int n = 0; n < 2; ++n) oacc[hh][dt][n] = mfma16(vf, wpk[n], oacc[hh][dt][n]);
        }
      }
    }
    // cross-head (cross-wave) Asum reduction, XOR-swizzled
#pragma unroll
    for (int mt = 0; mt < 4; ++mt)
#pragma unroll
      for (int n = 0; n < 2; ++n) {
        int q = n * 16 + li;
        int lc = (mt * 16 + 4 * g) ^ ((q & 7) << 2);
        *(f32x4*)&Part[w][q][lc] = asum[mt][n];
      }
    __syncthreads();
    {
      int q = t >> 4, l4 = (t & 15) * 4;
      int lc = l4 ^ ((q & 7) << 2);
      f32x4 sum = *(const f32x4*)&Part[0][q][lc];
#pragma unroll
      for (int wi = 1; wi < 8; ++wi) sum += *(const f32x4*)&Part[wi][q][lc];
      float4 o = make_float4(sum[0] * 0.0625f, sum[1] * 0.0625f, sum[2] * 0.0625f, sum[3] * 0.0625f);
      *(float4*)&ab[((size_t)(qt * 32 + q)) * LLL + lt * 64 + l4] = o;
    }
    __syncthreads();
  }

  // write O (out01): O^T C-layout: d = dt*16 + 4g + v, q = n*16 + li
#pragma unroll
  for (int hh = 0; hh < 2; ++hh)
#pragma unroll
    for (int dt = 0; dt < 4; ++dt)
#pragma unroll
      for (int n = 0; n < 2; ++n) {
        ushort4 us;
        us.x = f2b(oacc[hh][dt][n][0]);
        us.y = f2b(oacc[hh][dt][n][1]);
        us.z = f2b(oacc[hh][dt][n][2]);
        us.w = f2b(oacc[hh][dt][n][3]);
        *(ushort4*)&ob[((size_t)(qt * 32 + n * 16 + li)) * DIM +
                       (2 * w + hh) * HD + dt * 16 + 4 * g] = us;
      }
}

// ---------------- gated merge ----------------
__global__ void merge_kernel(const u16* __restrict__ o01,
                             const float* __restrict__ gate,
                             u16* __restrict__ merged) {
  int i = blockIdx.x * blockDim.x + threadIdx.x;
  float gv = gate[0];
  float g = 1.0f / (1.0f + __builtin_amdgcn_exp2f(-gv * LOG2E));
  const size_t n = (size_t)BB * SS * DIM;
  ushort4 a = ((const ushort4*)o01)[i];
  ushort4 c = ((const ushort4*)(o01 + n))[i];
  ushort4 o;
  o.x = f2b(g * b2f(a.x) + (1.f - g) * b2f(c.x));
  o.y = f2b(g * b2f(a.y) + (1.f - g) * b2f(c.y));
  o.z = f2b(g * b2f(a.z) + (1.f - g) * b2f(c.z));
  o.w = f2b(g * b2f(a.w) + (1.f - g) * b2f(c.w));
  ((ushort4*)merged)[i] = o;
}

extern "C" void kernel_launch(void* const* d_in, const int* in_sizes, int n_in,
                              void* d_out, int out_size, void* d_ws, size_t ws_size,
                              hipStream_t stream) {
  const float* query = (const float*)d_in[0];
  const float* k0f   = (const float*)d_in[1];
  const float* v0f   = (const float*)d_in[2];
  const float* k1f   = (const float*)d_in[3];
  const float* v1f   = (const float*)d_in[4];
  const int*   mask  = (const int*)d_in[5];
  const float* Wqf   = (const float*)d_in[6];
  const float* bq    = (const float*)d_in[7];
  const float* Wof   = (const float*)d_in[8];
  const float* bo    = (const float*)d_in[9];
  const float* gate  = (const float*)d_in[10];
  float* out = (float*)d_out;

  const size_t nQ = (size_t)BB * SS * DIM;
  const size_t nW = (size_t)DIM * DIM;

  char* ws = (char*)d_ws;
  size_t off = 0;
  auto alloc = [&](size_t bytes) -> char* {
    char* p = ws + off;
    off += (bytes + 255) & ~(size_t)255;
    return p;
  };
  u16*      queryb  = (u16*)alloc(nQ * 2);
  u16*      wqb     = (u16*)alloc(nW * 2);
  u16*      wob     = (u16*)alloc(nW * 2);
  u16*      kb0     = (u16*)alloc(nQ * 2);
  u16*      kb1     = (u16*)alloc(nQ * 2);
  u16*      qb      = (u16*)alloc(nQ * 2);
  u16*      Vt      = (u16*)alloc((size_t)2 * nQ * 2);       // [lay][b][h][d][L]
  unsigned* mbits   = (unsigned*)alloc((size_t)SS * (LLL / 32) * 4);
  u16*      out01   = (u16*)alloc((size_t)2 * nQ * 2);
  u16*      mergedb = (u16*)alloc(nQ * 2);

  auto cvt = [&](const float* s, u16* d, size_t n) {
    int n4 = (int)(n / 4);
    cvt_f32_bf16<<<dim3((n4 + 255) / 256), dim3(256), 0, stream>>>(s, d, n4);
  };
  cvt(query, queryb, nQ);
  cvt(Wqf, wqb, nW);
  cvt(Wof, wob, nW);
  cvt(k0f, kb0, nQ);
  cvt(k1f, kb1, nQ);

  mask_pack<<<dim3(SS * (LLL / 32) / 256), dim3(256), 0, stream>>>(mask, mbits);
  vtrans<<<dim3(LLL / 64, HEADS, 4), dim3(256), 0, stream>>>(v0f, v1f, Vt);

  gemm_nt<0><<<dim3(DIM / 64, (BB * SS) / 64), dim3(256), 0, stream>>>(
      queryb, wqb, bq, (void*)qb, BB * SS, DIM, DIM);

  attn_fused<<<dim3(256), dim3(512), 0, stream>>>(qb, kb0, kb1, Vt, mbits, out01, out + nQ);

  merge_kernel<<<dim3((int)(nQ / 4 / 256)), dim3(256), 0, stream>>>(out01, gate, mergedb);

  gemm_nt<1><<<dim3(DIM / 64, (BB * SS) / 64), dim3(256), 0, stream>>>(
      mergedb, wob, bo, (void*)out, BB * SS, DIM, DIM);
}

// Round 3
// 377.932 us; speedup vs baseline: 3.1784x; 1.9733x over previous
//
#include <hip/hip_runtime.h>

#define DIM   1024
#define HEADS 16
#define HD    64
#define BB    2
#define SS    2048
#define LLL   2048
#define LOG2E 1.4426950408889634f

typedef __bf16 bf16x8 __attribute__((ext_vector_type(8)));
typedef float  f32x4  __attribute__((ext_vector_type(4)));
typedef short  s16x4  __attribute__((ext_vector_type(4)));
typedef short  s16x8  __attribute__((ext_vector_type(8)));
typedef unsigned short u16;

static __device__ __forceinline__ u16 f2b(float x) {
  unsigned u = __float_as_uint(x);
  u += 0x7fffu + ((u >> 16) & 1u);
  return (u16)(u >> 16);
}
static __device__ __forceinline__ float b2f(u16 u) {
  return __uint_as_float(((unsigned)u) << 16);
}
static __device__ __forceinline__ f32x4 mfma32(bf16x8 a, bf16x8 b, f32x4 c) {
  return __builtin_amdgcn_mfma_f32_16x16x32_bf16(a, b, c, 0, 0, 0);
}
static __device__ __forceinline__ f32x4 mfma16(s16x4 a, s16x4 b, f32x4 c) {
#if __has_builtin(__builtin_amdgcn_mfma_f32_16x16x16bf16_1k)
  return __builtin_amdgcn_mfma_f32_16x16x16bf16_1k(a, b, c, 0, 0, 0);
#else
  asm volatile("v_mfma_f32_16x16x16_bf16 %0, %1, %2, %0" : "+v"(c) : "v"(a), "v"(b));
  return c;
#endif
}

// ---------------- f32 -> bf16 convert ----------------
__global__ void cvt_f32_bf16(const float* __restrict__ src, u16* __restrict__ dst, int n4) {
  int i = blockIdx.x * blockDim.x + threadIdx.x;
  if (i >= n4) return;
  float4 f = ((const float4*)src)[i];
  ushort4 o;
  o.x = f2b(f.x); o.y = f2b(f.y); o.z = f2b(f.z); o.w = f2b(f.w);
  ((ushort4*)dst)[i] = o;
}

// ---------------- mask -> bitmask ----------------
__global__ void mask_pack(const int* __restrict__ mask, unsigned* __restrict__ mbits) {
  int i = blockIdx.x * blockDim.x + threadIdx.x;
  const int* src = mask + (size_t)i * 32;
  unsigned bm = 0;
#pragma unroll
  for (int j = 0; j < 8; ++j) {
    int4 m = ((const int4*)src)[j];
    bm |= (m.x != 0 ? 1u : 0u) << (j * 4 + 0);
    bm |= (m.y != 0 ? 1u : 0u) << (j * 4 + 1);
    bm |= (m.z != 0 ? 1u : 0u) << (j * 4 + 2);
    bm |= (m.w != 0 ? 1u : 0u) << (j * 4 + 3);
  }
  mbits[i] = bm;
}

// ---------------- K (f32) -> fragment-packed bf16 tiles ----------------
// Kfrag[z][h][lt][c=mt*2+kk][lane][8]: lane(g,li) holds K[lt*64+mt*16+li][h*64+kk*32+g*8 ..+7]
__global__ __launch_bounds__(256) void pack_k(const float* __restrict__ k0,
                                              const float* __restrict__ k1,
                                              u16* __restrict__ Kfrag) {
  const int w = threadIdx.x >> 6, l = threadIdx.x & 63, g = l >> 4, li = l & 15;
  const int lt = blockIdx.x * 4 + w, h = blockIdx.y, z = blockIdx.z;
  const int lay = z >> 1, b = z & 1;
  const float* src = (lay ? k1 : k0) + (size_t)b * LLL * DIM;
  u16* dst = Kfrag + ((((size_t)z * HEADS + h) * 32 + lt) * 8) * 512;
#pragma unroll
  for (int c = 0; c < 8; ++c) {
    int mt = c >> 1, kk = c & 1;
    const float* p = &src[(size_t)(lt * 64 + mt * 16 + li) * DIM + h * 64 + kk * 32 + g * 8];
    float4 f0 = *(const float4*)p;
    float4 f1 = *(const float4*)(p + 4);
    u16 u[8] = {f2b(f0.x), f2b(f0.y), f2b(f0.z), f2b(f0.w),
                f2b(f1.x), f2b(f1.y), f2b(f1.z), f2b(f1.w)};
    *(uint4*)&dst[c * 512 + l * 8] = *(uint4*)u;
  }
}

// ---------------- V (f32) -> fragment-packed bf16 tiles (transposed) ----------------
// Vfrag[z][h][lt][c=mt*2+p][lane][8]: lane(g,li):
//   j=0..3: V^T[p*32+li][lt*64+mt*16+4g+j], j=4..7: V^T[p*32+16+li][lt*64+mt*16+4g+j]
__global__ __launch_bounds__(256) void pack_v(const float* __restrict__ v0,
                                              const float* __restrict__ v1,
                                              u16* __restrict__ Vfrag) {
  __shared__ u16 T[64][72];  // T[l][d]
  const int lt = blockIdx.x, h = blockIdx.y, z = blockIdx.z;
  const int lay = z >> 1, b = z & 1;
  const float* v = (lay ? v1 : v0) + (size_t)b * LLL * DIM;
  const int t = threadIdx.x;
  {
    int r = t >> 2, c16 = (t & 3) * 16;
    const float* src = &v[(size_t)(lt * 64 + r) * DIM + h * 64 + c16];
#pragma unroll
    for (int i = 0; i < 4; ++i) {
      float4 f = *(const float4*)&src[i * 4];
      T[r][c16 + i * 4 + 0] = f2b(f.x);
      T[r][c16 + i * 4 + 1] = f2b(f.y);
      T[r][c16 + i * 4 + 2] = f2b(f.z);
      T[r][c16 + i * 4 + 3] = f2b(f.w);
    }
  }
  __syncthreads();
  u16* dst = Vfrag + ((((size_t)z * HEADS + h) * 32 + lt) * 8) * 512;
  {
    int lane = t & 63, g = lane >> 4, li = lane & 15;
#pragma unroll
    for (int cc = 0; cc < 2; ++cc) {
      int c = (t >> 6) + cc * 4;
      int mt = c >> 1, p = c & 1;
      u16 u[8];
#pragma unroll
      for (int j = 0; j < 4; ++j) u[j] = T[mt * 16 + 4 * g + j][p * 32 + li];
#pragma unroll
      for (int j = 0; j < 4; ++j) u[4 + j] = T[mt * 16 + 4 * g + j][p * 32 + 16 + li];
      *(uint4*)&dst[c * 512 + lane * 8] = *(uint4*)u;
    }
  }
}

// ---------------- bf16 NT GEMM (swizzled LDS) ----------------
template<int F32OUT>
__global__ __launch_bounds__(256) void gemm_nt(const u16* __restrict__ A,
                                               const u16* __restrict__ Bt,
                                               const float* __restrict__ bias,
                                               void* __restrict__ Cv,
                                               int M, int N, int K) {
  __shared__ u16 As[64][64];
  __shared__ u16 Bs[64][64];
  const int t = threadIdx.x;
  const int w = t >> 6, l = t & 63, g = l >> 4, li = l & 15;
  const int m0 = blockIdx.y * 64, n0 = blockIdx.x * 64;
  f32x4 acc[4] = {};
  for (int kt = 0; kt < K; kt += 64) {
#pragma unroll
    for (int s = 0; s < 2; ++s) {
      int slot = t + s * 256;
      int r = slot >> 3, c8 = ((slot & 7) * 8) ^ ((r & 7) << 3);
      *(uint4*)&As[r][c8] = *(const uint4*)&A[(size_t)(m0 + r) * K + kt + ((slot & 7) * 8)];
      *(uint4*)&Bs[r][c8] = *(const uint4*)&Bt[(size_t)(n0 + r) * K + kt + ((slot & 7) * 8)];
    }
    __syncthreads();
#pragma unroll
    for (int kk = 0; kk < 2; ++kk) {
      int ra = w * 16 + li;
      bf16x8 a = *(const bf16x8*)&As[ra][(kk * 32 + g * 8) ^ ((ra & 7) << 3)];
#pragma unroll
      for (int ni = 0; ni < 4; ++ni) {
        int rb = ni * 16 + li;
        bf16x8 b = *(const bf16x8*)&Bs[rb][(kk * 32 + g * 8) ^ ((rb & 7) << 3)];
        acc[ni] = mfma32(a, b, acc[ni]);
      }
    }
    __syncthreads();
  }
#pragma unroll
  for (int ni = 0; ni < 4; ++ni)
#pragma unroll
    for (int v = 0; v < 4; ++v) {
      int rr = m0 + w * 16 + g * 4 + v;
      int cc = n0 + ni * 16 + li;
      float val = acc[ni][v] + bias[cc];
      if (F32OUT) ((float*)Cv)[(size_t)rr * N + cc] = val;
      else        ((u16*)Cv)[(size_t)rr * N + cc] = f2b(val);
    }
}

// ---------------- fused dual-pass attention (fragment-packed operands) ----------------
__global__ __launch_bounds__(512) void attn_fused(const u16* __restrict__ qb,
                                                  const u16* __restrict__ Kfrag,
                                                  const u16* __restrict__ Vfrag,
                                                  const unsigned* __restrict__ mbits,
                                                  u16* __restrict__ out01,
                                                  float* __restrict__ aout) {
  __shared__ float Part[8][32][64];
  const int flat = blockIdx.x;
  const int work = (flat & 7) * 32 + (flat >> 3);
  const int lay = work >> 7, b = (work >> 6) & 1, qt = work & 63;
  const int masked = (lay == 0);
  const int z = lay * 2 + b;
  u16* ob = out01 + ((size_t)z) * SS * DIM;
  float* ab = aout + ((size_t)z) * SS * LLL;

  const int t = threadIdx.x;
  const int w = t >> 6, l = t & 63, g = l >> 4, li = l & 15;
  const float SC = 0.125f * LOG2E;

  // per-wave fragment bases for this wave's two heads
  const u16* kfh[2];
  const u16* vfh[2];
#pragma unroll
  for (int hh = 0; hh < 2; ++hh) {
    size_t hb = ((((size_t)z * HEADS + 2 * w + hh) * 32) * 8) * 512;
    kfh[hh] = Kfrag + hb;
    vfh[hh] = Vfrag + hb;
  }

  // persistent Q fragments: Q[q=li+16n][d = h*64 + kk*32 + 8g..]
  bf16x8 qf[2][2][2];
  {
    const u16* qrow = qb + ((size_t)(b * SS + qt * 32)) * DIM;
#pragma unroll
    for (int hh = 0; hh < 2; ++hh)
#pragma unroll
      for (int n = 0; n < 2; ++n)
#pragma unroll
        for (int kk = 0; kk < 2; ++kk)
          qf[hh][n][kk] = *(const bf16x8*)&qrow[(size_t)(n * 16 + li) * DIM +
                                               (2 * w + hh) * HD + kk * 32 + g * 8];
  }

  // ---------- phase 1: denominators ----------
  float racc[2][2] = {};
  for (int lt = 0; lt < LLL / 64; ++lt) {
    unsigned mw[2][2];
    if (masked) {
#pragma unroll
      for (int n = 0; n < 2; ++n)
#pragma unroll
        for (int mh = 0; mh < 2; ++mh)
          mw[n][mh] = mbits[(size_t)(qt * 32 + n * 16 + li) * (LLL / 32) + lt * 2 + mh];
    }
#pragma unroll
    for (int hh = 0; hh < 2; ++hh) {
      f32x4 s[4][2] = {};
      __builtin_amdgcn_s_setprio(1);
#pragma unroll
      for (int mt = 0; mt < 4; ++mt)
#pragma unroll
        for (int kk = 0; kk < 2; ++kk) {
          bf16x8 kf = *(const bf16x8*)&kfh[hh][((size_t)lt * 8 + mt * 2 + kk) * 512 + l * 8];
#pragma unroll
          for (int n = 0; n < 2; ++n) s[mt][n] = mfma32(kf, qf[hh][n][kk], s[mt][n]);
        }
      __builtin_amdgcn_s_setprio(0);
#pragma unroll
      for (int mt = 0; mt < 4; ++mt)
#pragma unroll
        for (int n = 0; n < 2; ++n)
#pragma unroll
          for (int v = 0; v < 4; ++v) {
            float e = __builtin_amdgcn_exp2f(s[mt][n][v] * SC);
            if (masked && !((mw[n][mt >> 1] >> ((mt & 1) * 16 + 4 * g + v)) & 1u)) e = 0.f;
            racc[hh][n] += e;
          }
    }
  }
  float dinv[2][2];
#pragma unroll
  for (int hh = 0; hh < 2; ++hh)
#pragma unroll
    for (int n = 0; n < 2; ++n) {
      float r = racc[hh][n];
      r += __shfl_xor(r, 16);
      r += __shfl_xor(r, 32);
      dinv[hh][n] = 1.0f / r;
    }

  // ---------- phase 2: attention + head-mean ----------
  f32x4 oacc[2][4][2] = {};  // [hh][dt][n]
  for (int lt = 0; lt < LLL / 64; ++lt) {
    unsigned mw[2][2];
    if (masked) {
#pragma unroll
      for (int n = 0; n < 2; ++n)
#pragma unroll
        for (int mh = 0; mh < 2; ++mh)
          mw[n][mh] = mbits[(size_t)(qt * 32 + n * 16 + li) * (LLL / 32) + lt * 2 + mh];
    }
    f32x4 asum[4][2] = {};
#pragma unroll
    for (int hh = 0; hh < 2; ++hh) {
      f32x4 s[4][2] = {};
      __builtin_amdgcn_s_setprio(1);
#pragma unroll
      for (int mt = 0; mt < 4; ++mt)
#pragma unroll
        for (int kk = 0; kk < 2; ++kk) {
          bf16x8 kf = *(const bf16x8*)&kfh[hh][((size_t)lt * 8 + mt * 2 + kk) * 512 + l * 8];
#pragma unroll
          for (int n = 0; n < 2; ++n) s[mt][n] = mfma32(kf, qf[hh][n][kk], s[mt][n]);
        }
      __builtin_amdgcn_s_setprio(0);
#pragma unroll
      for (int mt = 0; mt < 4; ++mt) {
        s16x4 wpk[2];
#pragma unroll
        for (int n = 0; n < 2; ++n)
#pragma unroll
          for (int v = 0; v < 4; ++v) {
            float e = __builtin_amdgcn_exp2f(s[mt][n][v] * SC);
            if (masked && !((mw[n][mt >> 1] >> ((mt & 1) * 16 + 4 * g + v)) & 1u)) e = 0.f;
            e *= dinv[hh][n];
            asum[mt][n][v] += e;
            wpk[n][v] = (short)f2b(e);
          }
        __builtin_amdgcn_s_setprio(1);
#pragma unroll
        for (int p = 0; p < 2; ++p) {
          s16x8 vf = *(const s16x8*)&vfh[hh][((size_t)lt * 8 + mt * 2 + p) * 512 + l * 8];
          s16x4 lo = __builtin_shufflevector(vf, vf, 0, 1, 2, 3);
          s16x4 hi = __builtin_shufflevector(vf, vf, 4, 5, 6, 7);
#pragma unroll
          for (int n = 0; n < 2; ++n) {
            oacc[hh][2 * p + 0][n] = mfma16(lo, wpk[n], oacc[hh][2 * p + 0][n]);
            oacc[hh][2 * p + 1][n] = mfma16(hi, wpk[n], oacc[hh][2 * p + 1][n]);
          }
        }
        __builtin_amdgcn_s_setprio(0);
      }
    }
    // cross-head Asum reduction, XOR-swizzled LDS
#pragma unroll
    for (int mt = 0; mt < 4; ++mt)
#pragma unroll
      for (int n = 0; n < 2; ++n) {
        int q = n * 16 + li;
        int lc = (mt * 16 + 4 * g) ^ ((q & 7) << 2);
        *(f32x4*)&Part[w][q][lc] = asum[mt][n];
      }
    __syncthreads();
    {
      int q = t >> 4, l4 = (t & 15) * 4;
      int lc = l4 ^ ((q & 7) << 2);
      f32x4 sum = *(const f32x4*)&Part[0][q][lc];
#pragma unroll
      for (int wi = 1; wi < 8; ++wi) sum += *(const f32x4*)&Part[wi][q][lc];
      float4 o = make_float4(sum[0] * 0.0625f, sum[1] * 0.0625f, sum[2] * 0.0625f, sum[3] * 0.0625f);
      *(float4*)&ab[((size_t)(qt * 32 + q)) * LLL + lt * 64 + l4] = o;
    }
    __syncthreads();
  }

  // write O: O^T C-layout: d = dt*16 + 4g + v, q = n*16 + li
#pragma unroll
  for (int hh = 0; hh < 2; ++hh)
#pragma unroll
    for (int dt = 0; dt < 4; ++dt)
#pragma unroll
      for (int n = 0; n < 2; ++n) {
        ushort4 us;
        us.x = f2b(oacc[hh][dt][n][0]);
        us.y = f2b(oacc[hh][dt][n][1]);
        us.z = f2b(oacc[hh][dt][n][2]);
        us.w = f2b(oacc[hh][dt][n][3]);
        *(ushort4*)&ob[((size_t)(qt * 32 + n * 16 + li)) * DIM +
                       (2 * w + hh) * HD + dt * 16 + 4 * g] = us;
      }
}

// ---------------- gated merge ----------------
__global__ void merge_kernel(const u16* __restrict__ o01,
                             const float* __restrict__ gate,
                             u16* __restrict__ merged) {
  int i = blockIdx.x * blockDim.x + threadIdx.x;
  float gv = gate[0];
  float g = 1.0f / (1.0f + __builtin_amdgcn_exp2f(-gv * LOG2E));
  const size_t n = (size_t)BB * SS * DIM;
  ushort4 a = ((const ushort4*)o01)[i];
  ushort4 c = ((const ushort4*)(o01 + n))[i];
  ushort4 o;
  o.x = f2b(g * b2f(a.x) + (1.f - g) * b2f(c.x));
  o.y = f2b(g * b2f(a.y) + (1.f - g) * b2f(c.y));
  o.z = f2b(g * b2f(a.z) + (1.f - g) * b2f(c.z));
  o.w = f2b(g * b2f(a.w) + (1.f - g) * b2f(c.w));
  ((ushort4*)merged)[i] = o;
}

extern "C" void kernel_launch(void* const* d_in, const int* in_sizes, int n_in,
                              void* d_out, int out_size, void* d_ws, size_t ws_size,
                              hipStream_t stream) {
  const float* query = (const float*)d_in[0];
  const float* k0f   = (const float*)d_in[1];
  const float* v0f   = (const float*)d_in[2];
  const float* k1f   = (const float*)d_in[3];
  const float* v1f   = (const float*)d_in[4];
  const int*   mask  = (const int*)d_in[5];
  const float* Wqf   = (const float*)d_in[6];
  const float* bq    = (const float*)d_in[7];
  const float* Wof   = (const float*)d_in[8];
  const float* bo    = (const float*)d_in[9];
  const float* gate  = (const float*)d_in[10];
  float* out = (float*)d_out;

  const size_t nQ = (size_t)BB * SS * DIM;
  const size_t nW = (size_t)DIM * DIM;

  char* ws = (char*)d_ws;
  size_t off = 0;
  auto alloc = [&](size_t bytes) -> char* {
    char* p = ws + off;
    off += (bytes + 255) & ~(size_t)255;
    return p;
  };
  u16*      queryb  = (u16*)alloc(nQ * 2);
  u16*      wqb     = (u16*)alloc(nW * 2);
  u16*      wob     = (u16*)alloc(nW * 2);
  u16*      qb      = (u16*)alloc(nQ * 2);
  u16*      Kfrag   = (u16*)alloc((size_t)2 * nQ * 2);  // [z][h][lt][c][lane][8]
  u16*      Vfrag   = (u16*)alloc((size_t)2 * nQ * 2);
  unsigned* mbits   = (unsigned*)alloc((size_t)SS * (LLL / 32) * 4);
  u16*      out01   = (u16*)alloc((size_t)2 * nQ * 2);
  u16*      mergedb = (u16*)alloc(nQ * 2);

  auto cvt = [&](const float* s, u16* d, size_t n) {
    int n4 = (int)(n / 4);
    cvt_f32_bf16<<<dim3((n4 + 255) / 256), dim3(256), 0, stream>>>(s, d, n4);
  };
  cvt(query, queryb, nQ);
  cvt(Wqf, wqb, nW);
  cvt(Wof, wob, nW);

  mask_pack<<<dim3(SS * (LLL / 32) / 256), dim3(256), 0, stream>>>(mask, mbits);
  pack_k<<<dim3(LLL / 64 / 4, HEADS, 4), dim3(256), 0, stream>>>(k0f, k1f, Kfrag);
  pack_v<<<dim3(LLL / 64, HEADS, 4), dim3(256), 0, stream>>>(v0f, v1f, Vfrag);

  gemm_nt<0><<<dim3(DIM / 64, (BB * SS) / 64), dim3(256), 0, stream>>>(
      queryb, wqb, bq, (void*)qb, BB * SS, DIM, DIM);

  attn_fused<<<dim3(256), dim3(512), 0, stream>>>(qb, Kfrag, Vfrag, mbits, out01, out + nQ);

  merge_kernel<<<dim3((int)(nQ / 4 / 256)), dim3(256), 0, stream>>>(out01, gate, mergedb);

  gemm_nt<1><<<dim3(DIM / 64, (BB * SS) / 64), dim3(256), 0, stream>>>(
      mergedb, wob, bo, (void*)out, BB * SS, DIM, DIM);
}

// Round 4
// 357.856 us; speedup vs baseline: 3.3567x; 1.0561x over previous
//
#include <hip/hip_runtime.h>

#define DIM   1024
#define HEADS 16
#define HD    64
#define BB    2
#define SS    2048
#define LLL   2048
#define LOG2E 1.4426950408889634f

typedef __bf16 bf16x8 __attribute__((ext_vector_type(8)));
typedef __bf16 bf16x4v __attribute__((ext_vector_type(4)));
typedef float  f32x4  __attribute__((ext_vector_type(4)));
typedef short  s16x4  __attribute__((ext_vector_type(4)));
typedef short  s16x8  __attribute__((ext_vector_type(8)));
typedef unsigned short u16;

static __device__ __forceinline__ u16 f2b(float x) {
  unsigned u = __float_as_uint(x);
  u += 0x7fffu + ((u >> 16) & 1u);
  return (u16)(u >> 16);
}
static __device__ __forceinline__ float b2f(u16 u) {
  return __uint_as_float(((unsigned)u) << 16);
}
static __device__ __forceinline__ f32x4 mfma32(bf16x8 a, bf16x8 b, f32x4 c) {
  return __builtin_amdgcn_mfma_f32_16x16x32_bf16(a, b, c, 0, 0, 0);
}
static __device__ __forceinline__ f32x4 mfma16(s16x4 a, s16x4 b, f32x4 c) {
#if __has_builtin(__builtin_amdgcn_mfma_f32_16x16x16bf16_1k)
  return __builtin_amdgcn_mfma_f32_16x16x16bf16_1k(a, b, c, 0, 0, 0);
#else
  asm volatile("v_mfma_f32_16x16x16_bf16 %0, %1, %2, %0" : "+v"(c) : "v"(a), "v"(b));
  return c;
#endif
}

// e = exp2(s*SC + bias), bias = 0 if mask-bit set else -160 (=> e ~ 0)
template<int MASKED>
static __device__ __forceinline__ f32x4 expmask(f32x4 sv, unsigned mword, int shbase) {
  const float SC = 0.125f * LOG2E;
  f32x4 r;
  unsigned nib = MASKED ? ((mword >> shbase) & 0xFu) : 0u;
#pragma unroll
  for (int v = 0; v < 4; ++v) {
    float arg;
    if (MASKED) {
      int spread = ((int)(nib << (31 - v))) >> 31;            // all-ones if keep
      float bias = __uint_as_float((~(unsigned)spread) & 0xC3200000u);  // -160.0f if drop
      arg = __builtin_fmaf(sv[v], SC, bias);
    } else {
      arg = sv[v] * SC;
    }
    r[v] = __builtin_amdgcn_exp2f(arg);
  }
  return r;
}

// ---------------- f32 -> bf16 convert ----------------
__global__ void cvt_f32_bf16(const float* __restrict__ src, u16* __restrict__ dst, int n4) {
  int i = blockIdx.x * blockDim.x + threadIdx.x;
  if (i >= n4) return;
  float4 f = ((const float4*)src)[i];
  ushort4 o;
  o.x = f2b(f.x); o.y = f2b(f.y); o.z = f2b(f.z); o.w = f2b(f.w);
  ((ushort4*)dst)[i] = o;
}

// ---------------- mask -> bitmask ----------------
__global__ void mask_pack(const int* __restrict__ mask, unsigned* __restrict__ mbits) {
  int i = blockIdx.x * blockDim.x + threadIdx.x;
  const int* src = mask + (size_t)i * 32;
  unsigned bm = 0;
#pragma unroll
  for (int j = 0; j < 8; ++j) {
    int4 m = ((const int4*)src)[j];
    bm |= (m.x != 0 ? 1u : 0u) << (j * 4 + 0);
    bm |= (m.y != 0 ? 1u : 0u) << (j * 4 + 1);
    bm |= (m.z != 0 ? 1u : 0u) << (j * 4 + 2);
    bm |= (m.w != 0 ? 1u : 0u) << (j * 4 + 3);
  }
  mbits[i] = bm;
}

// ---------------- K (f32) -> fragment-packed bf16 tiles ----------------
__global__ __launch_bounds__(256) void pack_k(const float* __restrict__ k0,
                                              const float* __restrict__ k1,
                                              u16* __restrict__ Kfrag) {
  const int w = threadIdx.x >> 6, l = threadIdx.x & 63, g = l >> 4, li = l & 15;
  const int lt = blockIdx.x * 4 + w, h = blockIdx.y, z = blockIdx.z;
  const int lay = z >> 1, b = z & 1;
  const float* src = (lay ? k1 : k0) + (size_t)b * LLL * DIM;
  u16* dst = Kfrag + ((((size_t)z * HEADS + h) * 32 + lt) * 8) * 512;
#pragma unroll
  for (int c = 0; c < 8; ++c) {
    int mt = c >> 1, kk = c & 1;
    const float* p = &src[(size_t)(lt * 64 + mt * 16 + li) * DIM + h * 64 + kk * 32 + g * 8];
    float4 f0 = *(const float4*)p;
    float4 f1 = *(const float4*)(p + 4);
    u16 u[8] = {f2b(f0.x), f2b(f0.y), f2b(f0.z), f2b(f0.w),
                f2b(f1.x), f2b(f1.y), f2b(f1.z), f2b(f1.w)};
    *(uint4*)&dst[c * 512 + l * 8] = *(uint4*)u;
  }
}

// ---------------- V (f32) -> fragment-packed bf16 tiles (transposed) ----------------
__global__ __launch_bounds__(256) void pack_v(const float* __restrict__ v0,
                                              const float* __restrict__ v1,
                                              u16* __restrict__ Vfrag) {
  __shared__ u16 T[64][72];  // T[l][d]
  const int lt = blockIdx.x, h = blockIdx.y, z = blockIdx.z;
  const int lay = z >> 1, b = z & 1;
  const float* v = (lay ? v1 : v0) + (size_t)b * LLL * DIM;
  const int t = threadIdx.x;
  {
    int r = t >> 2, c16 = (t & 3) * 16;
    const float* src = &v[(size_t)(lt * 64 + r) * DIM + h * 64 + c16];
#pragma unroll
    for (int i = 0; i < 4; ++i) {
      float4 f = *(const float4*)&src[i * 4];
      T[r][c16 + i * 4 + 0] = f2b(f.x);
      T[r][c16 + i * 4 + 1] = f2b(f.y);
      T[r][c16 + i * 4 + 2] = f2b(f.z);
      T[r][c16 + i * 4 + 3] = f2b(f.w);
    }
  }
  __syncthreads();
  u16* dst = Vfrag + ((((size_t)z * HEADS + h) * 32 + lt) * 8) * 512;
  {
    int lane = t & 63, g = lane >> 4, li = lane & 15;
#pragma unroll
    for (int cc = 0; cc < 2; ++cc) {
      int c = (t >> 6) + cc * 4;
      int mt = c >> 1, p = c & 1;
      u16 u[8];
#pragma unroll
      for (int j = 0; j < 4; ++j) u[j] = T[mt * 16 + 4 * g + j][p * 32 + li];
#pragma unroll
      for (int j = 0; j < 4; ++j) u[4 + j] = T[mt * 16 + 4 * g + j][p * 32 + 16 + li];
      *(uint4*)&dst[c * 512 + lane * 8] = *(uint4*)u;
    }
  }
}

// ---------------- bf16 NT GEMM (swizzled LDS) ----------------
template<int F32OUT>
__global__ __launch_bounds__(256) void gemm_nt(const u16* __restrict__ A,
                                               const u16* __restrict__ Bt,
                                               const float* __restrict__ bias,
                                               void* __restrict__ Cv,
                                               int M, int N, int K) {
  __shared__ u16 As[64][64];
  __shared__ u16 Bs[64][64];
  const int t = threadIdx.x;
  const int w = t >> 6, l = t & 63, g = l >> 4, li = l & 15;
  const int m0 = blockIdx.y * 64, n0 = blockIdx.x * 64;
  f32x4 acc[4] = {};
  for (int kt = 0; kt < K; kt += 64) {
#pragma unroll
    for (int s = 0; s < 2; ++s) {
      int slot = t + s * 256;
      int r = slot >> 3, c8 = ((slot & 7) * 8) ^ ((r & 7) << 3);
      *(uint4*)&As[r][c8] = *(const uint4*)&A[(size_t)(m0 + r) * K + kt + ((slot & 7) * 8)];
      *(uint4*)&Bs[r][c8] = *(const uint4*)&Bt[(size_t)(n0 + r) * K + kt + ((slot & 7) * 8)];
    }
    __syncthreads();
#pragma unroll
    for (int kk = 0; kk < 2; ++kk) {
      int ra = w * 16 + li;
      bf16x8 a = *(const bf16x8*)&As[ra][(kk * 32 + g * 8) ^ ((ra & 7) << 3)];
#pragma unroll
      for (int ni = 0; ni < 4; ++ni) {
        int rb = ni * 16 + li;
        bf16x8 b = *(const bf16x8*)&Bs[rb][(kk * 32 + g * 8) ^ ((rb & 7) << 3)];
        acc[ni] = mfma32(a, b, acc[ni]);
      }
    }
    __syncthreads();
  }
#pragma unroll
  for (int ni = 0; ni < 4; ++ni)
#pragma unroll
    for (int v = 0; v < 4; ++v) {
      int rr = m0 + w * 16 + g * 4 + v;
      int cc = n0 + ni * 16 + li;
      float val = acc[ni][v] + bias[cc];
      if (F32OUT) ((float*)Cv)[(size_t)rr * N + cc] = val;
      else        ((u16*)Cv)[(size_t)rr * N + cc] = f2b(val);
    }
}

// ---------------- fused dual-pass attention: 16 waves, 1 head/wave ----------------
template<int MASKED>
static __device__ __forceinline__ void attn_body(int z, int qt, int t,
                                                 const u16* __restrict__ qb,
                                                 const u16* __restrict__ Kfrag,
                                                 const u16* __restrict__ Vfrag,
                                                 const unsigned* __restrict__ mbits,
                                                 u16* __restrict__ out01,
                                                 float* __restrict__ aout,
                                                 float (*Part)[32][64]) {
  const int w16 = t >> 6;  // wave index == head
  const int l = t & 63, g = l >> 4, li = l & 15;
  const int b = z & 1;
  const int h = w16;

  const u16* kfh = Kfrag + ((size_t)(z * HEADS + h)) * (32 * 8 * 512);
  const u16* vfh = Vfrag + ((size_t)(z * HEADS + h)) * (32 * 8 * 512);
  u16* ob = out01 + (size_t)z * SS * DIM;
  float* ab = aout + (size_t)z * SS * LLL;

  // persistent Q fragments: Q[q=n*16+li][d = h*64 + kk*32 + g*8 ..]
  bf16x8 qf[2][2];
  {
    const u16* qrow = qb + ((size_t)(b * SS + qt * 32)) * DIM + h * HD;
#pragma unroll
    for (int n = 0; n < 2; ++n)
#pragma unroll
      for (int kk = 0; kk < 2; ++kk)
        qf[n][kk] = *(const bf16x8*)&qrow[(size_t)(n * 16 + li) * DIM + kk * 32 + g * 8];
  }
  const unsigned* mrow0 = MASKED ? mbits + (size_t)(qt * 32 + li) * (LLL / 32) : nullptr;
  const unsigned* mrow1 = MASKED ? mrow0 + 16 * (LLL / 32) : nullptr;
  const int shb = 4 * g;

  // ---------- phase 1: denominators (wave-local, no barriers) ----------
  f32x4 racc4[2] = {};
  for (int lt = 0; lt < 32; ++lt) {
    unsigned mw[2][2];
    if (MASKED) {
      mw[0][0] = mrow0[lt * 2]; mw[0][1] = mrow0[lt * 2 + 1];
      mw[1][0] = mrow1[lt * 2]; mw[1][1] = mrow1[lt * 2 + 1];
    }
    const u16* kfl = kfh + (size_t)lt * 4096 + l * 8;
#pragma unroll
    for (int mt = 0; mt < 4; ++mt) {
      f32x4 s[2] = {};
      __builtin_amdgcn_s_setprio(1);
#pragma unroll
      for (int kk = 0; kk < 2; ++kk) {
        bf16x8 kf = *(const bf16x8*)&kfl[(mt * 2 + kk) * 512];
        s[0] = mfma32(kf, qf[0][kk], s[0]);
        s[1] = mfma32(kf, qf[1][kk], s[1]);
      }
      __builtin_amdgcn_s_setprio(0);
#pragma unroll
      for (int n = 0; n < 2; ++n)
        racc4[n] += expmask<MASKED>(s[n], MASKED ? mw[n][mt >> 1] : 0u, (mt & 1) * 16 + shb);
    }
  }
  float dinv[2];
#pragma unroll
  for (int n = 0; n < 2; ++n) {
    float r = racc4[n][0] + racc4[n][1] + racc4[n][2] + racc4[n][3];
    r += __shfl_xor(r, 16);
    r += __shfl_xor(r, 32);
    dinv[n] = 1.0f / r;
  }

  // ---------- phase 2: attention + head-mean ----------
  f32x4 oacc[4][2] = {};  // [dt][n], unnormalized
  for (int lt = 0; lt < 32; ++lt) {
    unsigned mw[2][2];
    if (MASKED) {
      mw[0][0] = mrow0[lt * 2]; mw[0][1] = mrow0[lt * 2 + 1];
      mw[1][0] = mrow1[lt * 2]; mw[1][1] = mrow1[lt * 2 + 1];
    }
    const u16* kfl = kfh + (size_t)lt * 4096 + l * 8;
    const u16* vfl = vfh + (size_t)lt * 4096 + l * 8;
    f32x4 asum[4][2];
#pragma unroll
    for (int mt = 0; mt < 4; ++mt) {
      f32x4 s[2] = {};
      __builtin_amdgcn_s_setprio(1);
#pragma unroll
      for (int kk = 0; kk < 2; ++kk) {
        bf16x8 kf = *(const bf16x8*)&kfl[(mt * 2 + kk) * 512];
        s[0] = mfma32(kf, qf[0][kk], s[0]);
        s[1] = mfma32(kf, qf[1][kk], s[1]);
      }
      __builtin_amdgcn_s_setprio(0);
      s16x4 wpk[2];
#pragma unroll
      for (int n = 0; n < 2; ++n) {
        f32x4 ev = expmask<MASKED>(s[n], MASKED ? mw[n][mt >> 1] : 0u, (mt & 1) * 16 + shb);
        bf16x4v wb = __builtin_convertvector(ev, bf16x4v);   // raw e (unnormalized)
        wpk[n] = __builtin_bit_cast(s16x4, wb);
        asum[mt][n] = ev * dinv[n];                           // normalized w for head-mean
      }
      __builtin_amdgcn_s_setprio(1);
#pragma unroll
      for (int p = 0; p < 2; ++p) {
        s16x8 vf = *(const s16x8*)&vfl[(mt * 2 + p) * 512];
        s16x4 lo = __builtin_shufflevector(vf, vf, 0, 1, 2, 3);
        s16x4 hi = __builtin_shufflevector(vf, vf, 4, 5, 6, 7);
#pragma unroll
        for (int n = 0; n < 2; ++n) {
          oacc[2 * p + 0][n] = mfma16(lo, wpk[n], oacc[2 * p + 0][n]);
          oacc[2 * p + 1][n] = mfma16(hi, wpk[n], oacc[2 * p + 1][n]);
        }
      }
      __builtin_amdgcn_s_setprio(0);
    }
    // cross-head Asum reduction (two-stage into 8 slabs)
    if (w16 < 8) {
#pragma unroll
      for (int mt = 0; mt < 4; ++mt)
#pragma unroll
        for (int n = 0; n < 2; ++n) {
          int q = n * 16 + li;
          int lc = (mt * 16 + 4 * g) ^ (li << 2);
          *(f32x4*)&Part[w16][q][lc] = asum[mt][n];
        }
    }
    __syncthreads();
    if (w16 >= 8) {
#pragma unroll
      for (int mt = 0; mt < 4; ++mt)
#pragma unroll
        for (int n = 0; n < 2; ++n) {
          int q = n * 16 + li;
          int lc = (mt * 16 + 4 * g) ^ (li << 2);
          f32x4* p = (f32x4*)&Part[w16 - 8][q][lc];
          *p += asum[mt][n];
        }
    }
    __syncthreads();
    if (t < 512) {
      int q = t >> 4, l4 = (t & 15) * 4;
      int lc = l4 ^ ((q & 15) << 2);
      f32x4 sum = *(const f32x4*)&Part[0][q][lc];
#pragma unroll
      for (int wi = 1; wi < 8; ++wi) sum += *(const f32x4*)&Part[wi][q][lc];
      float4 o = make_float4(sum[0] * 0.0625f, sum[1] * 0.0625f,
                             sum[2] * 0.0625f, sum[3] * 0.0625f);
      *(float4*)&ab[((size_t)(qt * 32 + q)) * LLL + lt * 64 + l4] = o;
    }
    __syncthreads();
  }

  // O epilogue: scale by dinv, pack, store
#pragma unroll
  for (int dt = 0; dt < 4; ++dt)
#pragma unroll
    for (int n = 0; n < 2; ++n) {
      f32x4 o = oacc[dt][n] * dinv[n];
      ushort4 us;
      us.x = f2b(o[0]); us.y = f2b(o[1]); us.z = f2b(o[2]); us.w = f2b(o[3]);
      *(ushort4*)&ob[((size_t)(qt * 32 + n * 16 + li)) * DIM + h * HD + dt * 16 + 4 * g] = us;
    }
}

__global__ __launch_bounds__(1024, 4) void attn_fused(const u16* __restrict__ qb,
                                                      const u16* __restrict__ Kfrag,
                                                      const u16* __restrict__ Vfrag,
                                                      const unsigned* __restrict__ mbits,
                                                      u16* __restrict__ out01,
                                                      float* __restrict__ aout) {
  __shared__ float Part[8][32][64];  // 64 KB
  const int flat = blockIdx.x;
  const int work = (flat & 7) * 32 + (flat >> 3);  // XCD-contiguous chunks
  const int z = work >> 6, qt = work & 63;
  if (z < 2) attn_body<1>(z, qt, threadIdx.x, qb, Kfrag, Vfrag, mbits, out01, aout, Part);
  else       attn_body<0>(z, qt, threadIdx.x, qb, Kfrag, Vfrag, mbits, out01, aout, Part);
}

// ---------------- gated merge ----------------
__global__ void merge_kernel(const u16* __restrict__ o01,
                             const float* __restrict__ gate,
                             u16* __restrict__ merged) {
  int i = blockIdx.x * blockDim.x + threadIdx.x;
  float gv = gate[0];
  float g = 1.0f / (1.0f + __builtin_amdgcn_exp2f(-gv * LOG2E));
  const size_t n = (size_t)BB * SS * DIM;
  ushort4 a = ((const ushort4*)o01)[i];
  ushort4 c = ((const ushort4*)(o01 + n))[i];
  ushort4 o;
  o.x = f2b(g * b2f(a.x) + (1.f - g) * b2f(c.x));
  o.y = f2b(g * b2f(a.y) + (1.f - g) * b2f(c.y));
  o.z = f2b(g * b2f(a.z) + (1.f - g) * b2f(c.z));
  o.w = f2b(g * b2f(a.w) + (1.f - g) * b2f(c.w));
  ((ushort4*)merged)[i] = o;
}

extern "C" void kernel_launch(void* const* d_in, const int* in_sizes, int n_in,
                              void* d_out, int out_size, void* d_ws, size_t ws_size,
                              hipStream_t stream) {
  const float* query = (const float*)d_in[0];
  const float* k0f   = (const float*)d_in[1];
  const float* v0f   = (const float*)d_in[2];
  const float* k1f   = (const float*)d_in[3];
  const float* v1f   = (const float*)d_in[4];
  const int*   mask  = (const int*)d_in[5];
  const float* Wqf   = (const float*)d_in[6];
  const float* bq    = (const float*)d_in[7];
  const float* Wof   = (const float*)d_in[8];
  const float* bo    = (const float*)d_in[9];
  const float* gate  = (const float*)d_in[10];
  float* out = (float*)d_out;

  const size_t nQ = (size_t)BB * SS * DIM;
  const size_t nW = (size_t)DIM * DIM;

  char* ws = (char*)d_ws;
  size_t off = 0;
  auto alloc = [&](size_t bytes) -> char* {
    char* p = ws + off;
    off += (bytes + 255) & ~(size_t)255;
    return p;
  };
  u16*      queryb  = (u16*)alloc(nQ * 2);
  u16*      wqb     = (u16*)alloc(nW * 2);
  u16*      wob     = (u16*)alloc(nW * 2);
  u16*      qb      = (u16*)alloc(nQ * 2);
  u16*      Kfrag   = (u16*)alloc((size_t)2 * nQ * 2);  // [z][h][lt][c][lane][8]
  u16*      Vfrag   = (u16*)alloc((size_t)2 * nQ * 2);
  unsigned* mbits   = (unsigned*)alloc((size_t)SS * (LLL / 32) * 4);
  u16*      out01   = (u16*)alloc((size_t)2 * nQ * 2);
  u16*      mergedb = (u16*)alloc(nQ * 2);

  auto cvt = [&](const float* s, u16* d, size_t n) {
    int n4 = (int)(n / 4);
    cvt_f32_bf16<<<dim3((n4 + 255) / 256), dim3(256), 0, stream>>>(s, d, n4);
  };
  cvt(query, queryb, nQ);
  cvt(Wqf, wqb, nW);
  cvt(Wof, wob, nW);

  mask_pack<<<dim3(SS * (LLL / 32) / 256), dim3(256), 0, stream>>>(mask, mbits);
  pack_k<<<dim3(LLL / 64 / 4, HEADS, 4), dim3(256), 0, stream>>>(k0f, k1f, Kfrag);
  pack_v<<<dim3(LLL / 64, HEADS, 4), dim3(256), 0, stream>>>(v0f, v1f, Vfrag);

  gemm_nt<0><<<dim3(DIM / 64, (BB * SS) / 64), dim3(256), 0, stream>>>(
      queryb, wqb, bq, (void*)qb, BB * SS, DIM, DIM);

  attn_fused<<<dim3(256), dim3(1024), 0, stream>>>(qb, Kfrag, Vfrag, mbits, out01, out + nQ);

  merge_kernel<<<dim3((int)(nQ / 4 / 256)), dim3(256), 0, stream>>>(out01, gate, mergedb);

  gemm_nt<1><<<dim3(DIM / 64, (BB * SS) / 64), dim3(256), 0, stream>>>(
      mergedb, wob, bo, (void*)out, BB * SS, DIM, DIM);
}

// Round 5
// 311.097 us; speedup vs baseline: 3.8612x; 1.1503x over previous
//
#include <hip/hip_runtime.h>

#define DIM   1024
#define HEADS 16
#define HD    64
#define BB    2
#define SS    2048
#define LLL   2048
#define LOG2E 1.4426950408889634f

typedef __bf16 bf16x8 __attribute__((ext_vector_type(8)));
typedef __bf16 bf16x4v __attribute__((ext_vector_type(4)));
typedef float  f32x4  __attribute__((ext_vector_type(4)));
typedef short  s16x4  __attribute__((ext_vector_type(4)));
typedef short  s16x8  __attribute__((ext_vector_type(8)));
typedef unsigned short u16;

static __device__ __forceinline__ u16 f2b(float x) {
  unsigned u = __float_as_uint(x);
  u += 0x7fffu + ((u >> 16) & 1u);
  return (u16)(u >> 16);
}
static __device__ __forceinline__ float b2f(u16 u) {
  return __uint_as_float(((unsigned)u) << 16);
}
static __device__ __forceinline__ f32x4 mfma32(bf16x8 a, bf16x8 b, f32x4 c) {
  return __builtin_amdgcn_mfma_f32_16x16x32_bf16(a, b, c, 0, 0, 0);
}
static __device__ __forceinline__ f32x4 mfma16(s16x4 a, s16x4 b, f32x4 c) {
#if __has_builtin(__builtin_amdgcn_mfma_f32_16x16x16bf16_1k)
  return __builtin_amdgcn_mfma_f32_16x16x16bf16_1k(a, b, c, 0, 0, 0);
#else
  asm volatile("v_mfma_f32_16x16x16_bf16 %0, %1, %2, %0" : "+v"(c) : "v"(a), "v"(b));
  return c;
#endif
}

// e = exp2(s*SC + bias), bias = 0 if mask-bit set else -160 (=> e ~ 0)
template<int MASKED>
static __device__ __forceinline__ f32x4 expmask(f32x4 sv, unsigned mword, int shbase) {
  const float SC = 0.125f * LOG2E;
  f32x4 r;
  unsigned nib = MASKED ? ((mword >> shbase) & 0xFu) : 0u;
#pragma unroll
  for (int v = 0; v < 4; ++v) {
    float arg;
    if (MASKED) {
      int spread = ((int)(nib << (31 - v))) >> 31;            // all-ones if keep
      float bias = __uint_as_float((~(unsigned)spread) & 0xC3200000u);  // -160.0f if drop
      arg = __builtin_fmaf(sv[v], SC, bias);
    } else {
      arg = sv[v] * SC;
    }
    r[v] = __builtin_amdgcn_exp2f(arg);
  }
  return r;
}

// ---------------- f32 -> bf16 convert ----------------
__global__ void cvt_f32_bf16(const float* __restrict__ src, u16* __restrict__ dst, int n4) {
  int i = blockIdx.x * blockDim.x + threadIdx.x;
  if (i >= n4) return;
  float4 f = ((const float4*)src)[i];
  ushort4 o;
  o.x = f2b(f.x); o.y = f2b(f.y); o.z = f2b(f.z); o.w = f2b(f.w);
  ((ushort4*)dst)[i] = o;
}

// ---------------- mask -> bitmask ----------------
__global__ void mask_pack(const int* __restrict__ mask, unsigned* __restrict__ mbits) {
  int i = blockIdx.x * blockDim.x + threadIdx.x;
  const int* src = mask + (size_t)i * 32;
  unsigned bm = 0;
#pragma unroll
  for (int j = 0; j < 8; ++j) {
    int4 m = ((const int4*)src)[j];
    bm |= (m.x != 0 ? 1u : 0u) << (j * 4 + 0);
    bm |= (m.y != 0 ? 1u : 0u) << (j * 4 + 1);
    bm |= (m.z != 0 ? 1u : 0u) << (j * 4 + 2);
    bm |= (m.w != 0 ? 1u : 0u) << (j * 4 + 3);
  }
  mbits[i] = bm;
}

// ---------------- K (f32) -> fragment-packed bf16 tiles ----------------
// Kfrag[z][h][lt][c=mt*2+kk][lane][8]: lane(g,li) holds K[lt*64+mt*16+li][h*64+kk*32+g*8..+7]
__global__ __launch_bounds__(256) void pack_k(const float* __restrict__ k0,
                                              const float* __restrict__ k1,
                                              u16* __restrict__ Kfrag) {
  const int w = threadIdx.x >> 6, l = threadIdx.x & 63, g = l >> 4, li = l & 15;
  const int lt = blockIdx.x * 4 + w, h = blockIdx.y, z = blockIdx.z;
  const int lay = z >> 1, b = z & 1;
  const float* src = (lay ? k1 : k0) + (size_t)b * LLL * DIM;
  u16* dst = Kfrag + ((((size_t)z * HEADS + h) * 32 + lt) * 8) * 512;
#pragma unroll
  for (int c = 0; c < 8; ++c) {
    int mt = c >> 1, kk = c & 1;
    const float* p = &src[(size_t)(lt * 64 + mt * 16 + li) * DIM + h * 64 + kk * 32 + g * 8];
    float4 f0 = *(const float4*)p;
    float4 f1 = *(const float4*)(p + 4);
    u16 u[8] = {f2b(f0.x), f2b(f0.y), f2b(f0.z), f2b(f0.w),
                f2b(f1.x), f2b(f1.y), f2b(f1.z), f2b(f1.w)};
    *(uint4*)&dst[c * 512 + l * 8] = *(uint4*)u;
  }
}

// ---------------- V (f32) -> fragment-packed bf16 tiles (transposed) ----------------
__global__ __launch_bounds__(256) void pack_v(const float* __restrict__ v0,
                                              const float* __restrict__ v1,
                                              u16* __restrict__ Vfrag) {
  __shared__ u16 T[64][72];  // T[l][d]
  const int lt = blockIdx.x, h = blockIdx.y, z = blockIdx.z;
  const int lay = z >> 1, b = z & 1;
  const float* v = (lay ? v1 : v0) + (size_t)b * LLL * DIM;
  const int t = threadIdx.x;
  {
    int r = t >> 2, c16 = (t & 3) * 16;
    const float* src = &v[(size_t)(lt * 64 + r) * DIM + h * 64 + c16];
#pragma unroll
    for (int i = 0; i < 4; ++i) {
      float4 f = *(const float4*)&src[i * 4];
      T[r][c16 + i * 4 + 0] = f2b(f.x);
      T[r][c16 + i * 4 + 1] = f2b(f.y);
      T[r][c16 + i * 4 + 2] = f2b(f.z);
      T[r][c16 + i * 4 + 3] = f2b(f.w);
    }
  }
  __syncthreads();
  u16* dst = Vfrag + ((((size_t)z * HEADS + h) * 32 + lt) * 8) * 512;
  {
    int lane = t & 63, g = lane >> 4, li = lane & 15;
#pragma unroll
    for (int cc = 0; cc < 2; ++cc) {
      int c = (t >> 6) + cc * 4;
      int mt = c >> 1, p = c & 1;
      u16 u[8];
#pragma unroll
      for (int j = 0; j < 4; ++j) u[j] = T[mt * 16 + 4 * g + j][p * 32 + li];
#pragma unroll
      for (int j = 0; j < 4; ++j) u[4 + j] = T[mt * 16 + 4 * g + j][p * 32 + 16 + li];
      *(uint4*)&dst[c * 512 + lane * 8] = *(uint4*)u;
    }
  }
}

// ---------------- bf16 NT GEMM (swizzled LDS). MODE 1: f32 row-major out; MODE 2: Q-fragment out
template<int MODE>
__global__ __launch_bounds__(256) void gemm_nt(const u16* __restrict__ A,
                                               const u16* __restrict__ Bt,
                                               const float* __restrict__ bias,
                                               void* __restrict__ Cv,
                                               int M, int N, int K) {
  __shared__ u16 As[64][64];
  __shared__ u16 Bs[64][64];
  const int t = threadIdx.x;
  const int w = t >> 6, l = t & 63, g = l >> 4, li = l & 15;
  const int m0 = blockIdx.y * 64, n0 = blockIdx.x * 64;
  f32x4 acc[4] = {};
  for (int kt = 0; kt < K; kt += 64) {
#pragma unroll
    for (int s = 0; s < 2; ++s) {
      int slot = t + s * 256;
      int r = slot >> 3, c8 = ((slot & 7) * 8) ^ ((r & 7) << 3);
      *(uint4*)&As[r][c8] = *(const uint4*)&A[(size_t)(m0 + r) * K + kt + ((slot & 7) * 8)];
      *(uint4*)&Bs[r][c8] = *(const uint4*)&Bt[(size_t)(n0 + r) * K + kt + ((slot & 7) * 8)];
    }
    __syncthreads();
#pragma unroll
    for (int kk = 0; kk < 2; ++kk) {
      int ra = w * 16 + li;
      bf16x8 a = *(const bf16x8*)&As[ra][(kk * 32 + g * 8) ^ ((ra & 7) << 3)];
#pragma unroll
      for (int ni = 0; ni < 4; ++ni) {
        int rb = ni * 16 + li;
        bf16x8 b = *(const bf16x8*)&Bs[rb][(kk * 32 + g * 8) ^ ((rb & 7) << 3)];
        acc[ni] = mfma32(a, b, acc[ni]);
      }
    }
    __syncthreads();
  }
#pragma unroll
  for (int ni = 0; ni < 4; ++ni)
#pragma unroll
    for (int v = 0; v < 4; ++v) {
      int rr = m0 + w * 16 + g * 4 + v;
      int cc = n0 + ni * 16 + li;
      float val = acc[ni][v] + bias[cc];
      if (MODE == 1) {
        ((float*)Cv)[(size_t)rr * N + cc] = val;
      } else {
        // Qfrag[b][h][qt][c=n*2+kk][lane(gp,liq)][8]
        int b = rr >> 11, q = rr & 2047;
        int qt = q >> 5, n = (q >> 4) & 1, liq = q & 15;
        int h = (cc >> 6) & 15, kk2 = (cc >> 5) & 1, gp = (cc >> 3) & 3, j = cc & 7;
        size_t base = ((((size_t)b * HEADS + h) * 64 + qt) * 4 + n * 2 + kk2) * 512;
        ((u16*)Cv)[base + (size_t)(gp * 16 + liq) * 8 + j] = f2b(val);
      }
    }
}

// ---------------- attn_pv: one pass, per-wave independent, no LDS/barriers ----------------
template<int MASKED>
static __device__ __forceinline__ void attn_pv_body(int z, int h, int qt, int l,
                                                    const u16* __restrict__ Qfrag,
                                                    const u16* __restrict__ Kfrag,
                                                    const u16* __restrict__ Vfrag,
                                                    const unsigned* __restrict__ mbits,
                                                    u16* __restrict__ out01,
                                                    float* __restrict__ db) {
  const int g = l >> 4, li = l & 15;
  const int b = z & 1;
  const u16* kfh = Kfrag + (size_t)(z * HEADS + h) * (32 * 8 * 512);
  const u16* vfh = Vfrag + (size_t)(z * HEADS + h) * (32 * 8 * 512);
  const u16* qfh = Qfrag + (((size_t)(b * HEADS + h) * 64 + qt) * 4) * 512;

  bf16x8 qf[2][2];
#pragma unroll
  for (int n = 0; n < 2; ++n)
#pragma unroll
    for (int kk = 0; kk < 2; ++kk)
      qf[n][kk] = *(const bf16x8*)&qfh[(n * 2 + kk) * 512 + l * 8];

  const unsigned* mrow0 = MASKED ? mbits + (size_t)(qt * 32 + li) * (LLL / 32) : nullptr;
  const unsigned* mrow1 = MASKED ? mrow0 + 16 * (LLL / 32) : nullptr;
  const int shb = 4 * g;

  f32x4 racc4[2] = {};
  f32x4 oacc[4][2] = {};  // [dt][n], unnormalized
  for (int lt = 0; lt < 32; ++lt) {
    unsigned mw[2][2];
    if (MASKED) {
      mw[0][0] = mrow0[lt * 2]; mw[0][1] = mrow0[lt * 2 + 1];
      mw[1][0] = mrow1[lt * 2]; mw[1][1] = mrow1[lt * 2 + 1];
    }
    const u16* kfl = kfh + (size_t)lt * 4096 + l * 8;
    const u16* vfl = vfh + (size_t)lt * 4096 + l * 8;
#pragma unroll
    for (int mt = 0; mt < 4; ++mt) {
      f32x4 s[2] = {};
      __builtin_amdgcn_s_setprio(1);
#pragma unroll
      for (int kk = 0; kk < 2; ++kk) {
        bf16x8 kf = *(const bf16x8*)&kfl[(mt * 2 + kk) * 512];
        s[0] = mfma32(kf, qf[0][kk], s[0]);
        s[1] = mfma32(kf, qf[1][kk], s[1]);
      }
      __builtin_amdgcn_s_setprio(0);
      s16x4 wpk[2];
#pragma unroll
      for (int n = 0; n < 2; ++n) {
        f32x4 ev = expmask<MASKED>(s[n], MASKED ? mw[n][mt >> 1] : 0u, (mt & 1) * 16 + shb);
        racc4[n] += ev;
        bf16x4v wb = __builtin_convertvector(ev, bf16x4v);
        wpk[n] = __builtin_bit_cast(s16x4, wb);
      }
      __builtin_amdgcn_s_setprio(1);
#pragma unroll
      for (int p = 0; p < 2; ++p) {
        s16x8 vf = *(const s16x8*)&vfl[(mt * 2 + p) * 512];
        s16x4 lo = __builtin_shufflevector(vf, vf, 0, 1, 2, 3);
        s16x4 hi = __builtin_shufflevector(vf, vf, 4, 5, 6, 7);
#pragma unroll
        for (int n = 0; n < 2; ++n) {
          oacc[2 * p + 0][n] = mfma16(lo, wpk[n], oacc[2 * p + 0][n]);
          oacc[2 * p + 1][n] = mfma16(hi, wpk[n], oacc[2 * p + 1][n]);
        }
      }
      __builtin_amdgcn_s_setprio(0);
    }
  }
  float dinv[2];
#pragma unroll
  for (int n = 0; n < 2; ++n) {
    float r = racc4[n][0] + racc4[n][1] + racc4[n][2] + racc4[n][3];
    r += __shfl_xor(r, 16);
    r += __shfl_xor(r, 32);
    dinv[n] = 1.0f / r;
  }
  if (l < 16) {
    float* dp = db + (size_t)(z * HEADS + h) * SS + qt * 32 + li;
    dp[0]  = dinv[0];
    dp[16] = dinv[1];
  }
  u16* ob = out01 + (size_t)z * SS * DIM;
#pragma unroll
  for (int dt = 0; dt < 4; ++dt)
#pragma unroll
    for (int n = 0; n < 2; ++n) {
      f32x4 o = oacc[dt][n] * dinv[n];
      ushort4 us;
      us.x = f2b(o[0]); us.y = f2b(o[1]); us.z = f2b(o[2]); us.w = f2b(o[3]);
      *(ushort4*)&ob[((size_t)(qt * 32 + n * 16 + li)) * DIM + h * HD + dt * 16 + 4 * g] = us;
    }
}

__global__ __launch_bounds__(256, 4) void attn_pv(const u16* __restrict__ Qfrag,
                                                  const u16* __restrict__ Kfrag,
                                                  const u16* __restrict__ Vfrag,
                                                  const unsigned* __restrict__ mbits,
                                                  u16* __restrict__ out01,
                                                  float* __restrict__ db) {
  const int flat = blockIdx.x;
  const int wb = (flat & 7) * 128 + (flat >> 3);  // XCD-contiguous chunks (1024 blocks)
  const int widx = wb * 4 + (threadIdx.x >> 6);
  const int z = widx >> 10, rem = widx & 1023;
  const int qt = rem >> 4, h = rem & 15;
  if (z < 2) attn_pv_body<1>(z, h, qt, threadIdx.x & 63, Qfrag, Kfrag, Vfrag, mbits, out01, db);
  else       attn_pv_body<0>(z, h, qt, threadIdx.x & 63, Qfrag, Kfrag, Vfrag, mbits, out01, db);
}

// ---------------- amean: head-mean attention map; one wave = all 16 heads of one S-tile ----------------
template<int MASKED>
static __device__ __forceinline__ void amean_body(int z, int qt, int lt, int l,
                                                  const u16* __restrict__ Qfrag,
                                                  const u16* __restrict__ Kfrag,
                                                  const unsigned* __restrict__ mbits,
                                                  const float* __restrict__ db,
                                                  float* __restrict__ aout) {
  const int g = l >> 4, li = l & 15;
  const int b = z & 1;
  const float SC = 0.125f * LOG2E;

  unsigned mw[2][2];
  if (MASKED) {
    const unsigned* m0 = mbits + (size_t)(qt * 32 + li) * (LLL / 32) + lt * 2;
    const unsigned* m1 = m0 + 16 * (LLL / 32);
    mw[0][0] = m0[0]; mw[0][1] = m0[1];
    mw[1][0] = m1[0]; mw[1][1] = m1[1];
  }
  const u16* kf_base = Kfrag + (size_t)(z * HEADS) * (32 * 8 * 512) + (size_t)lt * 4096 + l * 8;
  const u16* qf_base = Qfrag + (((size_t)(b * HEADS) * 64 + qt) * 4) * 512 + l * 8;
  const float* dbb = db + (size_t)(z * HEADS) * SS + qt * 32 + li;

  f32x4 asum[4][2] = {};
#pragma unroll 2
  for (int h = 0; h < HEADS; ++h) {
    float l2[2];
    l2[0] = __log2f(dbb[(size_t)h * SS]);
    l2[1] = __log2f(dbb[(size_t)h * SS + 16]);
    bf16x8 qf[2][2];
#pragma unroll
    for (int n = 0; n < 2; ++n)
#pragma unroll
      for (int kk = 0; kk < 2; ++kk)
        qf[n][kk] = *(const bf16x8*)&qf_base[(size_t)h * (64 * 4 * 512) + (n * 2 + kk) * 512];
    const u16* kfh = kf_base + (size_t)h * (32 * 8 * 512);
#pragma unroll
    for (int mt = 0; mt < 4; ++mt) {
      f32x4 s[2] = {};
#pragma unroll
      for (int kk = 0; kk < 2; ++kk) {
        bf16x8 kf = *(const bf16x8*)&kfh[(mt * 2 + kk) * 512];
        s[0] = mfma32(kf, qf[0][kk], s[0]);
        s[1] = mfma32(kf, qf[1][kk], s[1]);
      }
#pragma unroll
      for (int n = 0; n < 2; ++n) {
        unsigned mword = MASKED ? mw[n][mt >> 1] : 0u;
        int shb = (mt & 1) * 16 + 4 * g;
#pragma unroll
        for (int v = 0; v < 4; ++v) {
          float bias = l2[n];
          if (MASKED && !((mword >> (shb + v)) & 1u)) bias = -160.0f;
          asum[mt][n][v] += __builtin_amdgcn_exp2f(__builtin_fmaf(s[n][v], SC, bias));
        }
      }
    }
  }
  float* ab = aout + (size_t)z * SS * LLL;
#pragma unroll
  for (int mt = 0; mt < 4; ++mt)
#pragma unroll
    for (int n = 0; n < 2; ++n) {
      f32x4 o = asum[mt][n] * 0.0625f;
      *(f32x4*)&ab[(size_t)(qt * 32 + n * 16 + li) * LLL + lt * 64 + mt * 16 + 4 * g] = o;
    }
}

__global__ __launch_bounds__(256, 4) void amean(const u16* __restrict__ Qfrag,
                                                const u16* __restrict__ Kfrag,
                                                const unsigned* __restrict__ mbits,
                                                const float* __restrict__ db,
                                                float* __restrict__ aout) {
  const int flat = blockIdx.x;
  const int wb = (flat & 7) * 256 + (flat >> 3);  // XCD-contiguous chunks (2048 blocks)
  const int widx = wb * 4 + (threadIdx.x >> 6);
  const int z = widx >> 11, rem = widx & 2047;
  const int qt = rem >> 5, lt = rem & 31;
  if (z < 2) amean_body<1>(z, qt, lt, threadIdx.x & 63, Qfrag, Kfrag, mbits, db, aout);
  else       amean_body<0>(z, qt, lt, threadIdx.x & 63, Qfrag, Kfrag, mbits, db, aout);
}

// ---------------- gated merge ----------------
__global__ void merge_kernel(const u16* __restrict__ o01,
                             const float* __restrict__ gate,
                             u16* __restrict__ merged) {
  int i = blockIdx.x * blockDim.x + threadIdx.x;
  float gv = gate[0];
  float g = 1.0f / (1.0f + __builtin_amdgcn_exp2f(-gv * LOG2E));
  const size_t n = (size_t)BB * SS * DIM;
  ushort4 a = ((const ushort4*)o01)[i];
  ushort4 c = ((const ushort4*)(o01 + n))[i];
  ushort4 o;
  o.x = f2b(g * b2f(a.x) + (1.f - g) * b2f(c.x));
  o.y = f2b(g * b2f(a.y) + (1.f - g) * b2f(c.y));
  o.z = f2b(g * b2f(a.z) + (1.f - g) * b2f(c.z));
  o.w = f2b(g * b2f(a.w) + (1.f - g) * b2f(c.w));
  ((ushort4*)merged)[i] = o;
}

extern "C" void kernel_launch(void* const* d_in, const int* in_sizes, int n_in,
                              void* d_out, int out_size, void* d_ws, size_t ws_size,
                              hipStream_t stream) {
  const float* query = (const float*)d_in[0];
  const float* k0f   = (const float*)d_in[1];
  const float* v0f   = (const float*)d_in[2];
  const float* k1f   = (const float*)d_in[3];
  const float* v1f   = (const float*)d_in[4];
  const int*   mask  = (const int*)d_in[5];
  const float* Wqf   = (const float*)d_in[6];
  const float* bq    = (const float*)d_in[7];
  const float* Wof   = (const float*)d_in[8];
  const float* bo    = (const float*)d_in[9];
  const float* gate  = (const float*)d_in[10];
  float* out = (float*)d_out;

  const size_t nQ = (size_t)BB * SS * DIM;
  const size_t nW = (size_t)DIM * DIM;

  char* ws = (char*)d_ws;
  size_t off = 0;
  auto alloc = [&](size_t bytes) -> char* {
    char* p = ws + off;
    off += (bytes + 255) & ~(size_t)255;
    return p;
  };
  u16*      queryb  = (u16*)alloc(nQ * 2);             // reused as mergedb later
  u16*      wqb     = (u16*)alloc(nW * 2);
  u16*      wob     = (u16*)alloc(nW * 2);
  u16*      Qfrag   = (u16*)alloc(nQ * 2);             // [b][h][qt][c][lane][8]
  u16*      Kfrag   = (u16*)alloc((size_t)2 * nQ * 2); // [z][h][lt][c][lane][8]
  u16*      Vfrag   = (u16*)alloc((size_t)2 * nQ * 2);
  unsigned* mbits   = (unsigned*)alloc((size_t)SS * (LLL / 32) * 4);
  float*    db      = (float*)alloc((size_t)4 * HEADS * SS * 4);  // dinv per (z,h,q)
  u16*      out01   = (u16*)alloc((size_t)2 * nQ * 2);
  u16*      mergedb = queryb;  // queryb dead after gemm_q

  auto cvt = [&](const float* s, u16* d, size_t n) {
    int n4 = (int)(n / 4);
    cvt_f32_bf16<<<dim3((n4 + 255) / 256), dim3(256), 0, stream>>>(s, d, n4);
  };
  cvt(query, queryb, nQ);
  cvt(Wqf, wqb, nW);
  cvt(Wof, wob, nW);

  mask_pack<<<dim3(SS * (LLL / 32) / 256), dim3(256), 0, stream>>>(mask, mbits);
  pack_k<<<dim3(LLL / 64 / 4, HEADS, 4), dim3(256), 0, stream>>>(k0f, k1f, Kfrag);
  pack_v<<<dim3(LLL / 64, HEADS, 4), dim3(256), 0, stream>>>(v0f, v1f, Vfrag);

  // q projection straight into fragment layout
  gemm_nt<2><<<dim3(DIM / 64, (BB * SS) / 64), dim3(256), 0, stream>>>(
      queryb, wqb, bq, (void*)Qfrag, BB * SS, DIM, DIM);

  // fused single-pass attention (O + dinv), fully per-wave
  attn_pv<<<dim3(1024), dim3(256), 0, stream>>>(Qfrag, Kfrag, Vfrag, mbits, out01, db);

  // head-mean attention maps straight into d_out
  amean<<<dim3(2048), dim3(256), 0, stream>>>(Qfrag, Kfrag, mbits, db, out + nQ);

  merge_kernel<<<dim3((int)(nQ / 4 / 256)), dim3(256), 0, stream>>>(out01, gate, mergedb);

  gemm_nt<1><<<dim3(DIM / 64, (BB * SS) / 64), dim3(256), 0, stream>>>(
      mergedb, wob, bo, (void*)out, BB * SS, DIM, DIM);
}